// Round 8
// baseline (628.240 us; speedup 1.0000x reference)
//
#include <hip/hip_runtime.h>
#include <hip/hip_bf16.h>
#include <cstdint>
#include <cstddef>

// Problem constants
#define BB 4
#define SS 2048
#define DD 1024
#define HH 16
#define HDD 64

typedef __bf16 bf16_t;
typedef __bf16 bf16x8 __attribute__((ext_vector_type(8)));
typedef float f32x4 __attribute__((ext_vector_type(4)));

__device__ __forceinline__ unsigned short f2bf(float f) {
    unsigned u = __float_as_uint(f);
    unsigned r = (u + 0x7FFFu + ((u >> 16) & 1u)) >> 16;
    return (unsigned short)r;
}
__device__ __forceinline__ bf16_t f2bf16(float f) {
    return __builtin_bit_cast(bf16_t, f2bf(f));
}
__device__ __forceinline__ bf16x8 cvt8(float4 a, float4 b) {
    bf16x8 r;
    r[0] = f2bf16(a.x); r[1] = f2bf16(a.y);
    r[2] = f2bf16(a.z); r[3] = f2bf16(a.w);
    r[4] = f2bf16(b.x); r[5] = f2bf16(b.y);
    r[6] = f2bf16(b.z); r[7] = f2bf16(b.w);
    return r;
}

// async global->LDS, 16B per lane; LDS dest = wave-uniform base + lane*16
#define GLL16(gp, lp)                                                          \
    __builtin_amdgcn_global_load_lds(                                          \
        (const __attribute__((address_space(1))) void*)(gp),                   \
        (__attribute__((address_space(3))) void*)(lp), 16, 0, 0)

// padded stride for attn P tile (72 elem = 144 B): 16B-aligned rows, <=2-way
// bank aliasing on both the packed b32 writes and the b128 reads (free).
#define LSTR 72

// ---------------------------------------------------------------------------
// fp32 -> bf16 converters (memory-bound, one-shot)
// ---------------------------------------------------------------------------
__global__ __launch_bounds__(256) void cvt1(const float* __restrict__ in,
                                            bf16_t* __restrict__ out) {
    size_t i = (size_t)blockIdx.x * 256 + threadIdx.x;
    const float4* p = (const float4*)in + i * 2;
    *(bf16x8*)(out + i * 8) = cvt8(p[0], p[1]);
}
__global__ __launch_bounds__(256) void cvt4(
    const float* __restrict__ w0, const float* __restrict__ w1,
    const float* __restrict__ w2, const float* __restrict__ w3,
    bf16_t* __restrict__ o0, bf16_t* __restrict__ o1,
    bf16_t* __restrict__ o2, bf16_t* __restrict__ o3) {
    const float* in = blockIdx.y == 0 ? w0 : blockIdx.y == 1 ? w1
                    : blockIdx.y == 2 ? w2 : w3;
    bf16_t* out = blockIdx.y == 0 ? o0 : blockIdx.y == 1 ? o1
                : blockIdx.y == 2 ? o2 : o3;
    size_t i = (size_t)blockIdx.x * 256 + threadIdx.x;
    const float4* p = (const float4*)in + i * 2;
    *(bf16x8*)(out + i * 8) = cvt8(p[0], p[1]);
}

// ---------------------------------------------------------------------------
// Fused QKV GEMM: C(8192x3072) = x(8192x1024) @ W3^T, W3 = [wq;wk;wv] rows.
// Section (block-uniform, n0>>10): 0 -> Q rope (B,H,S,HD), 1 -> K rope,
// 2 -> V transposed (B,H,HD,S). m97-pattern GLL16 staging.
// ---------------------------------------------------------------------------
__global__ __launch_bounds__(256, 2) void gemm_qkv(
    const bf16_t* __restrict__ A, const bf16_t* __restrict__ W3,
    bf16_t* __restrict__ Qb, bf16_t* __restrict__ Kb, bf16_t* __restrict__ Vtb,
    const float* __restrict__ fcos, const float* __restrict__ fsin)
{
    constexpr int K = 1024;
    __shared__ alignas(16) bf16_t lA[128 * 64];
    __shared__ alignas(16) bf16_t lB[128 * 64];

    const int tid  = threadIdx.x;
    const int w    = tid >> 6;
    const int lane = tid & 63;
    const int quad = lane >> 4;
    const int l16  = lane & 15;
    const int wm   = w >> 1;
    const int wn   = w & 1;
    const int m0   = blockIdx.y * 128;
    const int n0   = blockIdx.x * 128;

    f32x4 acc[4][4];
#pragma unroll
    for (int i = 0; i < 4; i++)
#pragma unroll
        for (int j = 0; j < 4; j++) acc[i][j] = (f32x4){0.f, 0.f, 0.f, 0.f};

    const int srow8 = lane >> 3;
    const int slot  = lane & 7;

    for (int k0 = 0; k0 < K; k0 += 64) {
#pragma unroll
        for (int i = 0; i < 4; ++i) {
            int row = w * 32 + i * 8;
            GLL16(A + (size_t)(m0 + row + srow8) * K + k0 + slot * 8,
                  &lA[row * 64]);
            GLL16(W3 + (size_t)(n0 + row + srow8) * K + k0 + slot * 8,
                  &lB[row * 64]);
        }
        __syncthreads();
#pragma unroll
        for (int kk = 0; kk < 2; ++kk) {
            bf16x8 af[4], bfr[4];
#pragma unroll
            for (int mt = 0; mt < 4; ++mt)
                af[mt] = *(const bf16x8*)
                    &lA[(wm * 64 + mt * 16 + l16) * 64 + (kk * 4 + quad) * 8];
#pragma unroll
            for (int nt = 0; nt < 4; ++nt)
                bfr[nt] = *(const bf16x8*)
                    &lB[(wn * 64 + nt * 16 + l16) * 64 + (kk * 4 + quad) * 8];
#pragma unroll
            for (int mt = 0; mt < 4; ++mt)
#pragma unroll
                for (int nt = 0; nt < 4; ++nt)
                    acc[mt][nt] = __builtin_amdgcn_mfma_f32_16x16x32_bf16(
                        af[mt], bfr[nt], acc[mt][nt], 0, 0, 0);
        }
        __syncthreads();
    }

    const int sect = n0 >> 10;  // 0=Q,1=K,2=V (uniform per block)
    if (sect < 2) {
        unsigned short* Cu = (unsigned short*)(sect ? Kb : Qb);
#pragma unroll
        for (int mt = 0; mt < 4; ++mt) {
#pragma unroll
            for (int nt = 0; nt < 4; ++nt) {
                int col  = n0 + wn * 64 + nt * 16 + l16;
                int h    = (col >> 6) & 15;
                int d    = col & 63;
                int pidx = d >> 1;
                bool even = (col & 1) == 0;
#pragma unroll
                for (int r = 0; r < 4; ++r) {
                    int m = m0 + wm * 64 + mt * 16 + quad * 4 + r;
                    int b = m >> 11;   // / S
                    int s = m & 2047;  // % S
                    float v  = acc[mt][nt][r];
                    float p  = __shfl_xor(v, 1);
                    float c  = fcos[s * 32 + pidx];
                    float sn = fsin[s * 32 + pidx];
                    float o  = even ? (v * c - p * sn) : (p * sn + v * c);
                    float po = __shfl_xor(o, 1);  // partner's rotated value
                    if (even) {
                        unsigned pk = (unsigned)f2bf(o) |
                                      ((unsigned)f2bf(po) << 16);
                        *(unsigned*)&Cu[(size_t)((b * HH + h) * SS + s) * HDD + d] = pk;
                    }
                }
            }
        }
    } else {
        unsigned short* Cu = (unsigned short*)Vtb;
#pragma unroll
        for (int mt = 0; mt < 4; ++mt) {
#pragma unroll
            for (int nt = 0; nt < 4; ++nt) {
                int col = n0 + wn * 64 + nt * 16 + l16;
                int h = (col >> 6) & 15, d = col & 63;
#pragma unroll
                for (int r = 0; r < 4; ++r) {
                    int m = m0 + wm * 64 + mt * 16 + quad * 4 + r;
                    int b = m >> 11, s = m & 2047;
                    Cu[(size_t)((b * HH + h) * HDD + d) * SS + s] =
                        f2bf(acc[mt][nt][r]);
                }
            }
        }
    }
}

// ---------------------------------------------------------------------------
// Out-projection GEMM: d_out(8192x1024 fp32) = Ob(bf16) @ wo^T(bf16).
// ---------------------------------------------------------------------------
__global__ __launch_bounds__(256, 2) void gemm_out(
    const bf16_t* __restrict__ A, const bf16_t* __restrict__ W,
    float* __restrict__ Cf)
{
    constexpr int K = 1024, N = 1024;
    __shared__ alignas(16) bf16_t lA[128 * 64];
    __shared__ alignas(16) bf16_t lB[128 * 64];

    const int tid  = threadIdx.x;
    const int w    = tid >> 6;
    const int lane = tid & 63;
    const int quad = lane >> 4;
    const int l16  = lane & 15;
    const int wm   = w >> 1;
    const int wn   = w & 1;
    const int m0   = blockIdx.y * 128;
    const int n0   = blockIdx.x * 128;

    f32x4 acc[4][4];
#pragma unroll
    for (int i = 0; i < 4; i++)
#pragma unroll
        for (int j = 0; j < 4; j++) acc[i][j] = (f32x4){0.f, 0.f, 0.f, 0.f};

    const int srow8 = lane >> 3;
    const int slot  = lane & 7;

    for (int k0 = 0; k0 < K; k0 += 64) {
#pragma unroll
        for (int i = 0; i < 4; ++i) {
            int row = w * 32 + i * 8;
            GLL16(A + (size_t)(m0 + row + srow8) * K + k0 + slot * 8,
                  &lA[row * 64]);
            GLL16(W + (size_t)(n0 + row + srow8) * K + k0 + slot * 8,
                  &lB[row * 64]);
        }
        __syncthreads();
#pragma unroll
        for (int kk = 0; kk < 2; ++kk) {
            bf16x8 af[4], bfr[4];
#pragma unroll
            for (int mt = 0; mt < 4; ++mt)
                af[mt] = *(const bf16x8*)
                    &lA[(wm * 64 + mt * 16 + l16) * 64 + (kk * 4 + quad) * 8];
#pragma unroll
            for (int nt = 0; nt < 4; ++nt)
                bfr[nt] = *(const bf16x8*)
                    &lB[(wn * 64 + nt * 16 + l16) * 64 + (kk * 4 + quad) * 8];
#pragma unroll
            for (int mt = 0; mt < 4; ++mt)
#pragma unroll
                for (int nt = 0; nt < 4; ++nt)
                    acc[mt][nt] = __builtin_amdgcn_mfma_f32_16x16x32_bf16(
                        af[mt], bfr[nt], acc[mt][nt], 0, 0, 0);
        }
        __syncthreads();
    }

#pragma unroll
    for (int mt = 0; mt < 4; ++mt) {
        int mrow = m0 + wm * 64 + mt * 16 + quad * 4;
#pragma unroll
        for (int nt = 0; nt < 4; ++nt) {
            int col = n0 + wn * 64 + nt * 16 + l16;
#pragma unroll
            for (int r = 0; r < 4; ++r)
                Cf[(size_t)(mrow + r) * N + col] = acc[mt][nt][r];
        }
    }
}

// ---------------------------------------------------------------------------
// Flash attention v4 — barrier-free K-loop + k-parity wave split.
// Q,K (B,H,S,HD), Vt (B,H,HD,S), O (B,S,D). Direct-global K/V fragments
// (L2-served, XCD-affinity swizzle). Each 32-row q-tile is computed by TWO
// waves (even/odd k-blocks); no-max softmax partials (o, psum) combine
// linearly through LDS in the epilogue. Block = 2 tile-pairs x 2 parities;
// pairs (pg, 63-pg) total exactly 33 k-iters -> all 1024 blocks balanced,
// 4 blocks/CU all-resident.
// ---------------------------------------------------------------------------
__global__ __launch_bounds__(256, 4) void attn(
    const bf16_t* __restrict__ Q, const bf16_t* __restrict__ Kt,
    const bf16_t* __restrict__ Vt, bf16_t* __restrict__ O)
{
    const int tid  = threadIdx.x;
    const int w    = tid >> 6;
    const int lane = tid & 63;
    const int quad = lane >> 4;
    const int l16  = lane & 15;

    // Union: during the K-loop this is lP (wave-private P round-trip, bf16,
    // 4*32*LSTR*2 = 18432 B); during the epilogue combine it is the fp32
    // spill (2 pairs * 2560 floats = 20480 B). Phases separated by barriers.
    __shared__ alignas(16) char lsmem[20480];
    bf16_t* lP = (bf16_t*)lsmem;
    float*  lS = (float*)lsmem;

    // XCD-affinity decode
    const int blk  = blockIdx.x;          // 0..1023
    const int xcd  = blk & 7;
    const int rest = blk >> 3;            // 0..127
    const int g    = rest & 15;           // pair-group within bh
    const int bh   = (rest >> 4) * 8 + xcd;
    const int pair = w >> 1;              // 0 or 1
    const int par  = w & 1;               // k-parity
    const int pg   = g * 2 + pair;        // 0..31

    const float sscale = 0.125f * 1.44269504088896f;  // 1/sqrt(64)*log2(e)
    const int b = bh >> 4, h = bh & 15;
    unsigned short* Ou = (unsigned short*)O;
    bf16_t* lpw = &lP[w * 32 * LSTR];
    const bf16_t* Kb = Kt + (size_t)bh * SS * HDD;
    const bf16_t* Vb = Vt + (size_t)bh * HDD * SS;

    for (int half = 0; half < 2; ++half) {
        const int t   = half ? 63 - pg : pg;   // 32-row tile index
        const int q0  = t * 32;
        const int nkb = (t >> 1) + 1;

        bf16x8 qf[2][2];
#pragma unroll
        for (int qs = 0; qs < 2; ++qs) {
            const bf16_t* qp =
                Q + (size_t)(bh * SS + q0 + qs * 16 + l16) * HDD + quad * 8;
            qf[qs][0] = *(const bf16x8*)(qp);
            qf[qs][1] = *(const bf16x8*)(qp + 32);
        }

        f32x4 o[2][4];
        float ps[2][4];
#pragma unroll
        for (int qs = 0; qs < 2; ++qs)
#pragma unroll
            for (int i = 0; i < 4; ++i) {
                o[qs][i] = (f32x4){0.f, 0.f, 0.f, 0.f};
                ps[qs][i] = 0.f;
            }

        for (int ib = par; ib < nkb; ib += 2) {
            const int kb = ib * 64;
            const bool diag = (ib == nkb - 1);

            bf16x8 kf[4][2];
#pragma unroll
            for (int nt = 0; nt < 4; ++nt) {
                const bf16_t* kp =
                    Kb + (size_t)(kb + nt * 16 + l16) * HDD + quad * 8;
                kf[nt][0] = *(const bf16x8*)(kp);
                kf[nt][1] = *(const bf16x8*)(kp + 32);
            }
            bf16x8 vf[2][4];
#pragma unroll
            for (int kk = 0; kk < 2; ++kk)
#pragma unroll
                for (int nt = 0; nt < 4; ++nt)
                    vf[kk][nt] = *(const bf16x8*)
                        &Vb[(size_t)(nt * 16 + l16) * SS + kb + kk * 32 + quad * 8];

#pragma unroll
            for (int nt = 0; nt < 4; ++nt) {
                int colg = kb + nt * 16 + l16;
#pragma unroll
                for (int qs = 0; qs < 2; ++qs) {
                    f32x4 s = (f32x4){0.f, 0.f, 0.f, 0.f};
                    s = __builtin_amdgcn_mfma_f32_16x16x32_bf16(
                        qf[qs][0], kf[nt][0], s, 0, 0, 0);
                    s = __builtin_amdgcn_mfma_f32_16x16x32_bf16(
                        qf[qs][1], kf[nt][1], s, 0, 0, 0);
                    int rbase = q0 + qs * 16 + quad * 4;
#pragma unroll
                    for (int r = 0; r < 4; ++r) {
                        float sv = s[r];
                        if (diag && colg > rbase + r) sv = -1e30f;
                        float pv = exp2f(sv * sscale);
                        ps[qs][r] += pv;
                        float partner = __shfl_xor(pv, 1);
                        if ((lane & 1) == 0) {
                            unsigned pk = (__float_as_uint(pv) >> 16) |
                                          (__float_as_uint(partner) & 0xFFFF0000u);
                            int row = qs * 16 + quad * 4 + r;
                            *(unsigned*)&lpw[row * LSTR + nt * 16 + l16] = pk;
                        }
                    }
                }
            }

#pragma unroll
            for (int kk = 0; kk < 2; ++kk) {
                bf16x8 pf[2];
#pragma unroll
                for (int qs = 0; qs < 2; ++qs)
                    pf[qs] = *(const bf16x8*)
                        &lpw[(qs * 16 + l16) * LSTR + kk * 32 + quad * 8];
#pragma unroll
                for (int nt = 0; nt < 4; ++nt)
#pragma unroll
                    for (int qs = 0; qs < 2; ++qs)
                        o[qs][nt] = __builtin_amdgcn_mfma_f32_16x16x32_bf16(
                            pf[qs], vf[kk][nt], o[qs][nt], 0, 0, 0);
            }
        }

        // combine parity partials through LDS, then parity-0 wave writes out
        __syncthreads();
        float* sp = lS + pair * 2560;
        if (par) {
#pragma unroll
            for (int qs = 0; qs < 2; ++qs)
#pragma unroll
                for (int nt = 0; nt < 4; ++nt)
#pragma unroll
                    for (int j = 0; j < 4; ++j)
                        sp[(qs * 16 + nt * 4 + j) * 64 + lane] = o[qs][nt][j];
#pragma unroll
            for (int qs = 0; qs < 2; ++qs)
#pragma unroll
                for (int r = 0; r < 4; ++r)
                    sp[2048 + (qs * 4 + r) * 64 + lane] = ps[qs][r];
        }
        __syncthreads();
        if (!par) {
#pragma unroll
            for (int qs = 0; qs < 2; ++qs)
#pragma unroll
                for (int nt = 0; nt < 4; ++nt)
#pragma unroll
                    for (int j = 0; j < 4; ++j)
                        o[qs][nt][j] += sp[(qs * 16 + nt * 4 + j) * 64 + lane];
#pragma unroll
            for (int qs = 0; qs < 2; ++qs) {
                float lr[4];
#pragma unroll
                for (int r = 0; r < 4; ++r) {
                    float v = ps[qs][r] + sp[2048 + (qs * 4 + r) * 64 + lane];
                    v += __shfl_xor(v, 1);
                    v += __shfl_xor(v, 2);
                    v += __shfl_xor(v, 4);
                    v += __shfl_xor(v, 8);
                    lr[r] = v;
                }
#pragma unroll
                for (int nt = 0; nt < 4; ++nt) {
                    int d = nt * 16 + l16;
#pragma unroll
                    for (int r = 0; r < 4; ++r) {
                        int s = q0 + qs * 16 + quad * 4 + r;
                        float v = o[qs][nt][r] / lr[r];
                        Ou[(size_t)(b * SS + s) * DD + h * HDD + d] = f2bf(v);
                    }
                }
            }
        }
        __syncthreads();  // protect lsmem before next half reuses lP
    }
}

// ---------------------------------------------------------------------------
// Buffer plan.  TSZ = B*S*D bf16 = 16 MiB; WSZ = D*D bf16 = 2 MiB.
//   d_out (32 MiB fp32): [0,TSZ) = xb, [TSZ,2*TSZ) = Vt — both dead before
//     gemm_out overwrites d_out (it reads only Ob, wb3).
//   ws: Qb | Kb | Ob | wb0..3 = 56 MiB.  wb0..2 contiguous => W3 for QKV.
// ---------------------------------------------------------------------------
extern "C" void kernel_launch(void* const* d_in, const int* in_sizes, int n_in,
                              void* d_out, int out_size, void* d_ws,
                              size_t ws_size, hipStream_t stream)
{
    const float* x    = (const float*)d_in[0];
    const float* fcos = (const float*)d_in[1];
    const float* fsin = (const float*)d_in[2];
    const float* wq   = (const float*)d_in[3];
    const float* wk   = (const float*)d_in[4];
    const float* wv   = (const float*)d_in[5];
    const float* wo   = (const float*)d_in[6];

    char* ws = (char*)d_ws;
    const size_t TSZ = (size_t)BB * SS * DD * sizeof(bf16_t);  // 16 MiB
    const size_t WSZ = (size_t)DD * DD * sizeof(bf16_t);       // 2 MiB
    bf16_t* Qb  = (bf16_t*)(ws);
    bf16_t* Kb  = (bf16_t*)(ws + TSZ);
    bf16_t* Ob  = (bf16_t*)(ws + 2 * TSZ);
    bf16_t* wb0 = (bf16_t*)(ws + 3 * TSZ);
    bf16_t* wb1 = (bf16_t*)(ws + 3 * TSZ + WSZ);
    bf16_t* wb2 = (bf16_t*)(ws + 3 * TSZ + 2 * WSZ);
    bf16_t* wb3 = (bf16_t*)(ws + 3 * TSZ + 3 * WSZ);
    bf16_t* xb  = (bf16_t*)d_out;
    bf16_t* Vt  = (bf16_t*)((char*)d_out + TSZ);

    dim3 bb(256);
    cvt1<<<dim3(4096), bb, 0, stream>>>(x, xb);
    cvt4<<<dim3(512, 4), bb, 0, stream>>>(wq, wk, wv, wo, wb0, wb1, wb2, wb3);

    gemm_qkv<<<dim3(24, 64), bb, 0, stream>>>(xb, wb0, Qb, Kb, Vt, fcos, fsin);
    attn<<<dim3(1024), bb, 0, stream>>>(Qb, Kb, Vt, Ob);
    gemm_out<<<dim3(8, 64), bb, 0, stream>>>(Ob, wb3, (float*)d_out);
}

// Round 9
// 514.275 us; speedup vs baseline: 1.2216x; 1.2216x over previous
//
#include <hip/hip_runtime.h>
#include <hip/hip_bf16.h>
#include <cstdint>
#include <cstddef>

// Problem constants
#define BB 4
#define SS 2048
#define DD 1024
#define HH 16
#define HDD 64

typedef __bf16 bf16_t;
typedef __bf16 bf16x8 __attribute__((ext_vector_type(8)));
typedef float f32x4 __attribute__((ext_vector_type(4)));

__device__ __forceinline__ unsigned short f2bf(float f) {
    unsigned u = __float_as_uint(f);
    unsigned r = (u + 0x7FFFu + ((u >> 16) & 1u)) >> 16;
    return (unsigned short)r;
}
__device__ __forceinline__ bf16_t f2bf16(float f) {
    return __builtin_bit_cast(bf16_t, f2bf(f));
}
__device__ __forceinline__ bf16x8 cvt8(float4 a, float4 b) {
    bf16x8 r;
    r[0] = f2bf16(a.x); r[1] = f2bf16(a.y);
    r[2] = f2bf16(a.z); r[3] = f2bf16(a.w);
    r[4] = f2bf16(b.x); r[5] = f2bf16(b.y);
    r[6] = f2bf16(b.z); r[7] = f2bf16(b.w);
    return r;
}

// async global->LDS, 16B per lane; LDS dest = wave-uniform base + lane*16
#define GLL16(gp, lp)                                                          \
    __builtin_amdgcn_global_load_lds(                                          \
        (const __attribute__((address_space(1))) void*)(gp),                   \
        (__attribute__((address_space(3))) void*)(lp), 16, 0, 0)

// padded stride for attn P tile (72 elem = 144 B): 16B-aligned rows, <=2-way
// bank aliasing on both the packed b32 writes and the b128 reads (free).
#define LSTR 72

// ---------------------------------------------------------------------------
// fp32 -> bf16 converters (memory-bound, one-shot)
// ---------------------------------------------------------------------------
__global__ __launch_bounds__(256) void cvt1(const float* __restrict__ in,
                                            bf16_t* __restrict__ out) {
    size_t i = (size_t)blockIdx.x * 256 + threadIdx.x;
    const float4* p = (const float4*)in + i * 2;
    *(bf16x8*)(out + i * 8) = cvt8(p[0], p[1]);
}
__global__ __launch_bounds__(256) void cvt4(
    const float* __restrict__ w0, const float* __restrict__ w1,
    const float* __restrict__ w2, const float* __restrict__ w3,
    bf16_t* __restrict__ o0, bf16_t* __restrict__ o1,
    bf16_t* __restrict__ o2, bf16_t* __restrict__ o3) {
    const float* in = blockIdx.y == 0 ? w0 : blockIdx.y == 1 ? w1
                    : blockIdx.y == 2 ? w2 : w3;
    bf16_t* out = blockIdx.y == 0 ? o0 : blockIdx.y == 1 ? o1
                : blockIdx.y == 2 ? o2 : o3;
    size_t i = (size_t)blockIdx.x * 256 + threadIdx.x;
    const float4* p = (const float4*)in + i * 2;
    *(bf16x8*)(out + i * 8) = cvt8(p[0], p[1]);
}

// ---------------------------------------------------------------------------
// Fused QKV GEMM: C(8192x3072) = x(8192x1024) @ W3^T, W3 = [wq;wk;wv] rows.
// Section (block-uniform, n0>>10): 0 -> Q rope (B,H,S,HD), 1 -> K rope,
// 2 -> V transposed (B,H,HD,S). m97-pattern GLL16 staging.
// ---------------------------------------------------------------------------
__global__ __launch_bounds__(256, 2) void gemm_qkv(
    const bf16_t* __restrict__ A, const bf16_t* __restrict__ W3,
    bf16_t* __restrict__ Qb, bf16_t* __restrict__ Kb, bf16_t* __restrict__ Vtb,
    const float* __restrict__ fcos, const float* __restrict__ fsin)
{
    constexpr int K = 1024;
    __shared__ alignas(16) bf16_t lA[128 * 64];
    __shared__ alignas(16) bf16_t lB[128 * 64];

    const int tid  = threadIdx.x;
    const int w    = tid >> 6;
    const int lane = tid & 63;
    const int quad = lane >> 4;
    const int l16  = lane & 15;
    const int wm   = w >> 1;
    const int wn   = w & 1;
    const int m0   = blockIdx.y * 128;
    const int n0   = blockIdx.x * 128;

    f32x4 acc[4][4];
#pragma unroll
    for (int i = 0; i < 4; i++)
#pragma unroll
        for (int j = 0; j < 4; j++) acc[i][j] = (f32x4){0.f, 0.f, 0.f, 0.f};

    const int srow8 = lane >> 3;
    const int slot  = lane & 7;

    for (int k0 = 0; k0 < K; k0 += 64) {
#pragma unroll
        for (int i = 0; i < 4; ++i) {
            int row = w * 32 + i * 8;
            GLL16(A + (size_t)(m0 + row + srow8) * K + k0 + slot * 8,
                  &lA[row * 64]);
            GLL16(W3 + (size_t)(n0 + row + srow8) * K + k0 + slot * 8,
                  &lB[row * 64]);
        }
        __syncthreads();
#pragma unroll
        for (int kk = 0; kk < 2; ++kk) {
            bf16x8 af[4], bfr[4];
#pragma unroll
            for (int mt = 0; mt < 4; ++mt)
                af[mt] = *(const bf16x8*)
                    &lA[(wm * 64 + mt * 16 + l16) * 64 + (kk * 4 + quad) * 8];
#pragma unroll
            for (int nt = 0; nt < 4; ++nt)
                bfr[nt] = *(const bf16x8*)
                    &lB[(wn * 64 + nt * 16 + l16) * 64 + (kk * 4 + quad) * 8];
#pragma unroll
            for (int mt = 0; mt < 4; ++mt)
#pragma unroll
                for (int nt = 0; nt < 4; ++nt)
                    acc[mt][nt] = __builtin_amdgcn_mfma_f32_16x16x32_bf16(
                        af[mt], bfr[nt], acc[mt][nt], 0, 0, 0);
        }
        __syncthreads();
    }

    const int sect = n0 >> 10;  // 0=Q,1=K,2=V (uniform per block)
    if (sect < 2) {
        unsigned short* Cu = (unsigned short*)(sect ? Kb : Qb);
#pragma unroll
        for (int mt = 0; mt < 4; ++mt) {
#pragma unroll
            for (int nt = 0; nt < 4; ++nt) {
                int col  = n0 + wn * 64 + nt * 16 + l16;
                int h    = (col >> 6) & 15;
                int d    = col & 63;
                int pidx = d >> 1;
                bool even = (col & 1) == 0;
#pragma unroll
                for (int r = 0; r < 4; ++r) {
                    int m = m0 + wm * 64 + mt * 16 + quad * 4 + r;
                    int b = m >> 11;   // / S
                    int s = m & 2047;  // % S
                    float v  = acc[mt][nt][r];
                    float p  = __shfl_xor(v, 1);
                    float c  = fcos[s * 32 + pidx];
                    float sn = fsin[s * 32 + pidx];
                    float o  = even ? (v * c - p * sn) : (p * sn + v * c);
                    float po = __shfl_xor(o, 1);  // partner's rotated value
                    if (even) {
                        unsigned pk = (unsigned)f2bf(o) |
                                      ((unsigned)f2bf(po) << 16);
                        *(unsigned*)&Cu[(size_t)((b * HH + h) * SS + s) * HDD + d] = pk;
                    }
                }
            }
        }
    } else {
        unsigned short* Cu = (unsigned short*)Vtb;
#pragma unroll
        for (int mt = 0; mt < 4; ++mt) {
#pragma unroll
            for (int nt = 0; nt < 4; ++nt) {
                int col = n0 + wn * 64 + nt * 16 + l16;
                int h = (col >> 6) & 15, d = col & 63;
#pragma unroll
                for (int r = 0; r < 4; ++r) {
                    int m = m0 + wm * 64 + mt * 16 + quad * 4 + r;
                    int b = m >> 11, s = m & 2047;
                    Cu[(size_t)((b * HH + h) * HDD + d) * SS + s] =
                        f2bf(acc[mt][nt][r]);
                }
            }
        }
    }
}

// ---------------------------------------------------------------------------
// Out-projection GEMM: d_out(8192x1024 fp32) = Ob(bf16) @ wo^T(bf16).
// ---------------------------------------------------------------------------
__global__ __launch_bounds__(256, 2) void gemm_out(
    const bf16_t* __restrict__ A, const bf16_t* __restrict__ W,
    float* __restrict__ Cf)
{
    constexpr int K = 1024, N = 1024;
    __shared__ alignas(16) bf16_t lA[128 * 64];
    __shared__ alignas(16) bf16_t lB[128 * 64];

    const int tid  = threadIdx.x;
    const int w    = tid >> 6;
    const int lane = tid & 63;
    const int quad = lane >> 4;
    const int l16  = lane & 15;
    const int wm   = w >> 1;
    const int wn   = w & 1;
    const int m0   = blockIdx.y * 128;
    const int n0   = blockIdx.x * 128;

    f32x4 acc[4][4];
#pragma unroll
    for (int i = 0; i < 4; i++)
#pragma unroll
        for (int j = 0; j < 4; j++) acc[i][j] = (f32x4){0.f, 0.f, 0.f, 0.f};

    const int srow8 = lane >> 3;
    const int slot  = lane & 7;

    for (int k0 = 0; k0 < K; k0 += 64) {
#pragma unroll
        for (int i = 0; i < 4; ++i) {
            int row = w * 32 + i * 8;
            GLL16(A + (size_t)(m0 + row + srow8) * K + k0 + slot * 8,
                  &lA[row * 64]);
            GLL16(W + (size_t)(n0 + row + srow8) * K + k0 + slot * 8,
                  &lB[row * 64]);
        }
        __syncthreads();
#pragma unroll
        for (int kk = 0; kk < 2; ++kk) {
            bf16x8 af[4], bfr[4];
#pragma unroll
            for (int mt = 0; mt < 4; ++mt)
                af[mt] = *(const bf16x8*)
                    &lA[(wm * 64 + mt * 16 + l16) * 64 + (kk * 4 + quad) * 8];
#pragma unroll
            for (int nt = 0; nt < 4; ++nt)
                bfr[nt] = *(const bf16x8*)
                    &lB[(wn * 64 + nt * 16 + l16) * 64 + (kk * 4 + quad) * 8];
#pragma unroll
            for (int mt = 0; mt < 4; ++mt)
#pragma unroll
                for (int nt = 0; nt < 4; ++nt)
                    acc[mt][nt] = __builtin_amdgcn_mfma_f32_16x16x32_bf16(
                        af[mt], bfr[nt], acc[mt][nt], 0, 0, 0);
        }
        __syncthreads();
    }

#pragma unroll
    for (int mt = 0; mt < 4; ++mt) {
        int mrow = m0 + wm * 64 + mt * 16 + quad * 4;
#pragma unroll
        for (int nt = 0; nt < 4; ++nt) {
            int col = n0 + wn * 64 + nt * 16 + l16;
#pragma unroll
            for (int r = 0; r < 4; ++r)
                Cf[(size_t)(mrow + r) * N + col] = acc[mt][nt][r];
        }
    }
}

// ---------------------------------------------------------------------------
// Flash attention v5 — round-7 per-wave program, launched as ONE-WAVE blocks.
// 2048 x 64-thread blocks -> ~16 resident waves/CU (2x round-7 TLP) without
// touching the 92-VGPR budget (launch_bounds(64,4) caps at 128, no spill).
// Q,K (B,H,S,HD), Vt (B,H,HD,S), O (B,S,D). Direct-global K/V B-operand
// fragments (L2-served, XCD-affinity swizzle). Each wave owns paired 32-row
// q-tiles (pg, 63-pg): exactly 33 k-iters, balanced, fully independent.
// Only LDS: wave-private P round-trip (no barriers anywhere).
// ---------------------------------------------------------------------------
__global__ __launch_bounds__(64, 4) void attn(
    const bf16_t* __restrict__ Q, const bf16_t* __restrict__ Kt,
    const bf16_t* __restrict__ Vt, bf16_t* __restrict__ O)
{
    const int lane = threadIdx.x;
    const int quad = lane >> 4;
    const int l16  = lane & 15;

    __shared__ alignas(16) bf16_t lP[32 * LSTR];  // 4.6 KiB, wave-private

    // XCD-affinity decode: all blocks of a given bh land on XCD bh&7.
    const int blk  = blockIdx.x;          // 0..2047
    const int xcd  = blk & 7;
    const int rest = blk >> 3;            // 0..255
    const int pg   = rest & 31;           // pair index 0..31
    const int bh   = (rest >> 5) * 8 + xcd;

    const float sscale = 0.125f * 1.44269504088896f;  // 1/sqrt(64)*log2(e)
    const int b = bh >> 4, h = bh & 15;
    unsigned short* Ou = (unsigned short*)O;
    const bf16_t* Kb = Kt + (size_t)bh * SS * HDD;
    const bf16_t* Vb = Vt + (size_t)bh * HDD * SS;

    for (int half = 0; half < 2; ++half) {
        const int t   = half ? 63 - pg : pg;   // 32-row tile index
        const int q0  = t * 32;
        const int nkb = (t >> 1) + 1;

        // Q fragments: 2 subtiles x 2 k-chunks, straight from global
        bf16x8 qf[2][2];
#pragma unroll
        for (int qs = 0; qs < 2; ++qs) {
            const bf16_t* qp =
                Q + (size_t)(bh * SS + q0 + qs * 16 + l16) * HDD + quad * 8;
            qf[qs][0] = *(const bf16x8*)(qp);
            qf[qs][1] = *(const bf16x8*)(qp + 32);
        }

        f32x4 o[2][4];
        float ps[2][4];
#pragma unroll
        for (int qs = 0; qs < 2; ++qs)
#pragma unroll
            for (int i = 0; i < 4; ++i) {
                o[qs][i] = (f32x4){0.f, 0.f, 0.f, 0.f};
                ps[qs][i] = 0.f;
            }

        for (int ib = 0; ib < nkb; ++ib) {
            const int kb = ib * 64;
            const bool diag = (ib == nkb - 1);

            // K fragments (B-operand), direct global loads
            bf16x8 kf[4][2];
#pragma unroll
            for (int nt = 0; nt < 4; ++nt) {
                const bf16_t* kp =
                    Kb + (size_t)(kb + nt * 16 + l16) * HDD + quad * 8;
                kf[nt][0] = *(const bf16x8*)(kp);
                kf[nt][1] = *(const bf16x8*)(kp + 32);
            }
            // V fragments (B-operand), independent of P -> issue early
            bf16x8 vf[2][4];
#pragma unroll
            for (int kk = 0; kk < 2; ++kk)
#pragma unroll
                for (int nt = 0; nt < 4; ++nt)
                    vf[kk][nt] = *(const bf16x8*)
                        &Vb[(size_t)(nt * 16 + l16) * SS + kb + kk * 32 + quad * 8];

            // scores + exp + packed P write
#pragma unroll
            for (int nt = 0; nt < 4; ++nt) {
                int colg = kb + nt * 16 + l16;
#pragma unroll
                for (int qs = 0; qs < 2; ++qs) {
                    f32x4 s = (f32x4){0.f, 0.f, 0.f, 0.f};
                    s = __builtin_amdgcn_mfma_f32_16x16x32_bf16(
                        qf[qs][0], kf[nt][0], s, 0, 0, 0);
                    s = __builtin_amdgcn_mfma_f32_16x16x32_bf16(
                        qf[qs][1], kf[nt][1], s, 0, 0, 0);
                    int rbase = q0 + qs * 16 + quad * 4;
#pragma unroll
                    for (int r = 0; r < 4; ++r) {
                        float sv = s[r];
                        if (diag && colg > rbase + r) sv = -1e30f;
                        float pv = exp2f(sv * sscale);
                        ps[qs][r] += pv;
                        float partner = __shfl_xor(pv, 1);
                        if ((lane & 1) == 0) {
                            // truncating bf16 pack
                            unsigned pk = (__float_as_uint(pv) >> 16) |
                                          (__float_as_uint(partner) & 0xFFFF0000u);
                            int row = qs * 16 + quad * 4 + r;
                            *(unsigned*)&lP[row * LSTR + nt * 16 + l16] = pk;
                        }
                    }
                }
            }

            // PV: O += P @ V  (wave-private LDS RAW; per-wave DS in-order)
#pragma unroll
            for (int kk = 0; kk < 2; ++kk) {
                bf16x8 pf[2];
#pragma unroll
                for (int qs = 0; qs < 2; ++qs)
                    pf[qs] = *(const bf16x8*)
                        &lP[(qs * 16 + l16) * LSTR + kk * 32 + quad * 8];
#pragma unroll
                for (int nt = 0; nt < 4; ++nt)
#pragma unroll
                    for (int qs = 0; qs < 2; ++qs)
                        o[qs][nt] = __builtin_amdgcn_mfma_f32_16x16x32_bf16(
                            pf[qs], vf[kk][nt], o[qs][nt], 0, 0, 0);
            }
        }

        // epilogue: cross-lane row-sum reduce, O/l, write bf16 (B,S,D)
#pragma unroll
        for (int qs = 0; qs < 2; ++qs) {
            float lr[4];
#pragma unroll
            for (int r = 0; r < 4; ++r) {
                float v = ps[qs][r];
                v += __shfl_xor(v, 1);
                v += __shfl_xor(v, 2);
                v += __shfl_xor(v, 4);
                v += __shfl_xor(v, 8);
                lr[r] = v;
            }
#pragma unroll
            for (int nt = 0; nt < 4; ++nt) {
                int d = nt * 16 + l16;
#pragma unroll
                for (int r = 0; r < 4; ++r) {
                    int s = q0 + qs * 16 + quad * 4 + r;
                    float v = o[qs][nt][r] / lr[r];
                    Ou[(size_t)(b * SS + s) * DD + h * HDD + d] = f2bf(v);
                }
            }
        }
    }
}

// ---------------------------------------------------------------------------
// Buffer plan.  TSZ = B*S*D bf16 = 16 MiB; WSZ = D*D bf16 = 2 MiB.
//   d_out (32 MiB fp32): [0,TSZ) = xb, [TSZ,2*TSZ) = Vt — both dead before
//     gemm_out overwrites d_out (it reads only Ob, wb3).
//   ws: Qb | Kb | Ob | wb0..3 = 56 MiB.  wb0..2 contiguous => W3 for QKV.
// ---------------------------------------------------------------------------
extern "C" void kernel_launch(void* const* d_in, const int* in_sizes, int n_in,
                              void* d_out, int out_size, void* d_ws,
                              size_t ws_size, hipStream_t stream)
{
    const float* x    = (const float*)d_in[0];
    const float* fcos = (const float*)d_in[1];
    const float* fsin = (const float*)d_in[2];
    const float* wq   = (const float*)d_in[3];
    const float* wk   = (const float*)d_in[4];
    const float* wv   = (const float*)d_in[5];
    const float* wo   = (const float*)d_in[6];

    char* ws = (char*)d_ws;
    const size_t TSZ = (size_t)BB * SS * DD * sizeof(bf16_t);  // 16 MiB
    const size_t WSZ = (size_t)DD * DD * sizeof(bf16_t);       // 2 MiB
    bf16_t* Qb  = (bf16_t*)(ws);
    bf16_t* Kb  = (bf16_t*)(ws + TSZ);
    bf16_t* Ob  = (bf16_t*)(ws + 2 * TSZ);
    bf16_t* wb0 = (bf16_t*)(ws + 3 * TSZ);
    bf16_t* wb1 = (bf16_t*)(ws + 3 * TSZ + WSZ);
    bf16_t* wb2 = (bf16_t*)(ws + 3 * TSZ + 2 * WSZ);
    bf16_t* wb3 = (bf16_t*)(ws + 3 * TSZ + 3 * WSZ);
    bf16_t* xb  = (bf16_t*)d_out;
    bf16_t* Vt  = (bf16_t*)((char*)d_out + TSZ);

    dim3 bb(256);
    cvt1<<<dim3(4096), bb, 0, stream>>>(x, xb);
    cvt4<<<dim3(512, 4), bb, 0, stream>>>(wq, wk, wv, wo, wb0, wb1, wb2, wb3);

    gemm_qkv<<<dim3(24, 64), bb, 0, stream>>>(xb, wb0, Qb, Kb, Vt, fcos, fsin);
    attn<<<dim3(2048), dim3(64), 0, stream>>>(Qb, Kb, Vt, Ob);
    gemm_out<<<dim3(8, 64), bb, 0, stream>>>(Ob, wb3, (float*)d_out);
}

// Round 10
// 415.998 us; speedup vs baseline: 1.5102x; 1.2362x over previous
//
#include <hip/hip_runtime.h>
#include <hip/hip_bf16.h>
#include <cstdint>
#include <cstddef>

// Problem constants
#define BB 4
#define SS 2048
#define DD 1024
#define HH 16
#define HDD 64

typedef __bf16 bf16_t;
typedef __bf16 bf16x8 __attribute__((ext_vector_type(8)));
typedef float f32x4 __attribute__((ext_vector_type(4)));

__device__ __forceinline__ unsigned short f2bf(float f) {
    unsigned u = __float_as_uint(f);
    unsigned r = (u + 0x7FFFu + ((u >> 16) & 1u)) >> 16;
    return (unsigned short)r;
}
__device__ __forceinline__ bf16_t f2bf16(float f) {
    return __builtin_bit_cast(bf16_t, f2bf(f));
}
__device__ __forceinline__ bf16x8 cvt8(float4 a, float4 b) {
    bf16x8 r;
    r[0] = f2bf16(a.x); r[1] = f2bf16(a.y);
    r[2] = f2bf16(a.z); r[3] = f2bf16(a.w);
    r[4] = f2bf16(b.x); r[5] = f2bf16(b.y);
    r[6] = f2bf16(b.z); r[7] = f2bf16(b.w);
    return r;
}

// async global->LDS, 16B per lane; LDS dest = wave-uniform base + lane*16
#define GLL16(gp, lp)                                                          \
    __builtin_amdgcn_global_load_lds(                                          \
        (const __attribute__((address_space(1))) void*)(gp),                   \
        (__attribute__((address_space(3))) void*)(lp), 16, 0, 0)

// padded stride for attn P tile (72 elem = 144 B): 16B-aligned rows, <=2-way
// bank aliasing on both the packed b32 writes and the b128 reads (free).
#define LSTR 72

// ---------------------------------------------------------------------------
// fp32 -> bf16 converters (memory-bound, one-shot)
// ---------------------------------------------------------------------------
__global__ __launch_bounds__(256) void cvt1(const float* __restrict__ in,
                                            bf16_t* __restrict__ out) {
    size_t i = (size_t)blockIdx.x * 256 + threadIdx.x;
    const float4* p = (const float4*)in + i * 2;
    *(bf16x8*)(out + i * 8) = cvt8(p[0], p[1]);
}
__global__ __launch_bounds__(256) void cvt4(
    const float* __restrict__ w0, const float* __restrict__ w1,
    const float* __restrict__ w2, const float* __restrict__ w3,
    bf16_t* __restrict__ o0, bf16_t* __restrict__ o1,
    bf16_t* __restrict__ o2, bf16_t* __restrict__ o3) {
    const float* in = blockIdx.y == 0 ? w0 : blockIdx.y == 1 ? w1
                    : blockIdx.y == 2 ? w2 : w3;
    bf16_t* out = blockIdx.y == 0 ? o0 : blockIdx.y == 1 ? o1
                : blockIdx.y == 2 ? o2 : o3;
    size_t i = (size_t)blockIdx.x * 256 + threadIdx.x;
    const float4* p = (const float4*)in + i * 2;
    *(bf16x8*)(out + i * 8) = cvt8(p[0], p[1]);
}

// ---------------------------------------------------------------------------
// Fused QKV GEMM: C(8192x3072) = x(8192x1024) @ W3^T, W3 = [wq;wk;wv] rows.
// Section (block-uniform, n0>>10): 0 -> Q rope (B,H,S,HD), 1 -> K rope,
// 2 -> V transposed (B,H,HD,S). m97-pattern GLL16 staging.
// ---------------------------------------------------------------------------
__global__ __launch_bounds__(256, 2) void gemm_qkv(
    const bf16_t* __restrict__ A, const bf16_t* __restrict__ W3,
    bf16_t* __restrict__ Qb, bf16_t* __restrict__ Kb, bf16_t* __restrict__ Vtb,
    const float* __restrict__ fcos, const float* __restrict__ fsin)
{
    constexpr int K = 1024;
    __shared__ alignas(16) bf16_t lA[128 * 64];
    __shared__ alignas(16) bf16_t lB[128 * 64];

    const int tid  = threadIdx.x;
    const int w    = tid >> 6;
    const int lane = tid & 63;
    const int quad = lane >> 4;
    const int l16  = lane & 15;
    const int wm   = w >> 1;
    const int wn   = w & 1;
    const int m0   = blockIdx.y * 128;
    const int n0   = blockIdx.x * 128;

    f32x4 acc[4][4];
#pragma unroll
    for (int i = 0; i < 4; i++)
#pragma unroll
        for (int j = 0; j < 4; j++) acc[i][j] = (f32x4){0.f, 0.f, 0.f, 0.f};

    const int srow8 = lane >> 3;
    const int slot  = lane & 7;

    for (int k0 = 0; k0 < K; k0 += 64) {
#pragma unroll
        for (int i = 0; i < 4; ++i) {
            int row = w * 32 + i * 8;
            GLL16(A + (size_t)(m0 + row + srow8) * K + k0 + slot * 8,
                  &lA[row * 64]);
            GLL16(W3 + (size_t)(n0 + row + srow8) * K + k0 + slot * 8,
                  &lB[row * 64]);
        }
        __syncthreads();
#pragma unroll
        for (int kk = 0; kk < 2; ++kk) {
            bf16x8 af[4], bfr[4];
#pragma unroll
            for (int mt = 0; mt < 4; ++mt)
                af[mt] = *(const bf16x8*)
                    &lA[(wm * 64 + mt * 16 + l16) * 64 + (kk * 4 + quad) * 8];
#pragma unroll
            for (int nt = 0; nt < 4; ++nt)
                bfr[nt] = *(const bf16x8*)
                    &lB[(wn * 64 + nt * 16 + l16) * 64 + (kk * 4 + quad) * 8];
#pragma unroll
            for (int mt = 0; mt < 4; ++mt)
#pragma unroll
                for (int nt = 0; nt < 4; ++nt)
                    acc[mt][nt] = __builtin_amdgcn_mfma_f32_16x16x32_bf16(
                        af[mt], bfr[nt], acc[mt][nt], 0, 0, 0);
        }
        __syncthreads();
    }

    const int sect = n0 >> 10;  // 0=Q,1=K,2=V (uniform per block)
    if (sect < 2) {
        unsigned short* Cu = (unsigned short*)(sect ? Kb : Qb);
#pragma unroll
        for (int mt = 0; mt < 4; ++mt) {
#pragma unroll
            for (int nt = 0; nt < 4; ++nt) {
                int col  = n0 + wn * 64 + nt * 16 + l16;
                int h    = (col >> 6) & 15;
                int d    = col & 63;
                int pidx = d >> 1;
                bool even = (col & 1) == 0;
#pragma unroll
                for (int r = 0; r < 4; ++r) {
                    int m = m0 + wm * 64 + mt * 16 + quad * 4 + r;
                    int b = m >> 11;   // / S
                    int s = m & 2047;  // % S
                    float v  = acc[mt][nt][r];
                    float p  = __shfl_xor(v, 1);
                    float c  = fcos[s * 32 + pidx];
                    float sn = fsin[s * 32 + pidx];
                    float o  = even ? (v * c - p * sn) : (p * sn + v * c);
                    float po = __shfl_xor(o, 1);  // partner's rotated value
                    if (even) {
                        unsigned pk = (unsigned)f2bf(o) |
                                      ((unsigned)f2bf(po) << 16);
                        *(unsigned*)&Cu[(size_t)((b * HH + h) * SS + s) * HDD + d] = pk;
                    }
                }
            }
        }
    } else {
        unsigned short* Cu = (unsigned short*)Vtb;
#pragma unroll
        for (int mt = 0; mt < 4; ++mt) {
#pragma unroll
            for (int nt = 0; nt < 4; ++nt) {
                int col = n0 + wn * 64 + nt * 16 + l16;
                int h = (col >> 6) & 15, d = col & 63;
#pragma unroll
                for (int r = 0; r < 4; ++r) {
                    int m = m0 + wm * 64 + mt * 16 + quad * 4 + r;
                    int b = m >> 11, s = m & 2047;
                    Cu[(size_t)((b * HH + h) * HDD + d) * SS + s] =
                        f2bf(acc[mt][nt][r]);
                }
            }
        }
    }
}

// ---------------------------------------------------------------------------
// Out-projection GEMM: d_out(8192x1024 fp32) = Ob(bf16) @ wo^T(bf16).
// ---------------------------------------------------------------------------
__global__ __launch_bounds__(256, 2) void gemm_out(
    const bf16_t* __restrict__ A, const bf16_t* __restrict__ W,
    float* __restrict__ Cf)
{
    constexpr int K = 1024, N = 1024;
    __shared__ alignas(16) bf16_t lA[128 * 64];
    __shared__ alignas(16) bf16_t lB[128 * 64];

    const int tid  = threadIdx.x;
    const int w    = tid >> 6;
    const int lane = tid & 63;
    const int quad = lane >> 4;
    const int l16  = lane & 15;
    const int wm   = w >> 1;
    const int wn   = w & 1;
    const int m0   = blockIdx.y * 128;
    const int n0   = blockIdx.x * 128;

    f32x4 acc[4][4];
#pragma unroll
    for (int i = 0; i < 4; i++)
#pragma unroll
        for (int j = 0; j < 4; j++) acc[i][j] = (f32x4){0.f, 0.f, 0.f, 0.f};

    const int srow8 = lane >> 3;
    const int slot  = lane & 7;

    for (int k0 = 0; k0 < K; k0 += 64) {
#pragma unroll
        for (int i = 0; i < 4; ++i) {
            int row = w * 32 + i * 8;
            GLL16(A + (size_t)(m0 + row + srow8) * K + k0 + slot * 8,
                  &lA[row * 64]);
            GLL16(W + (size_t)(n0 + row + srow8) * K + k0 + slot * 8,
                  &lB[row * 64]);
        }
        __syncthreads();
#pragma unroll
        for (int kk = 0; kk < 2; ++kk) {
            bf16x8 af[4], bfr[4];
#pragma unroll
            for (int mt = 0; mt < 4; ++mt)
                af[mt] = *(const bf16x8*)
                    &lA[(wm * 64 + mt * 16 + l16) * 64 + (kk * 4 + quad) * 8];
#pragma unroll
            for (int nt = 0; nt < 4; ++nt)
                bfr[nt] = *(const bf16x8*)
                    &lB[(wn * 64 + nt * 16 + l16) * 64 + (kk * 4 + quad) * 8];
#pragma unroll
            for (int mt = 0; mt < 4; ++mt)
#pragma unroll
                for (int nt = 0; nt < 4; ++nt)
                    acc[mt][nt] = __builtin_amdgcn_mfma_f32_16x16x32_bf16(
                        af[mt], bfr[nt], acc[mt][nt], 0, 0, 0);
        }
        __syncthreads();
    }

#pragma unroll
    for (int mt = 0; mt < 4; ++mt) {
        int mrow = m0 + wm * 64 + mt * 16 + quad * 4;
#pragma unroll
        for (int nt = 0; nt < 4; ++nt) {
            int col = n0 + wn * 64 + nt * 16 + l16;
#pragma unroll
            for (int r = 0; r < 4; ++r)
                Cf[(size_t)(mrow + r) * N + col] = acc[mt][nt][r];
        }
    }
}

// ---------------------------------------------------------------------------
// Flash attention v6 — round-7 per-wave program, ONE 32-row q-tile per wave.
// 4096 waves total (2x round-7 TLP -> ~16 waves/CU). Blocks = 128 threads /
// 2 waves on adjacent tiles (2g, 2g+1) which have IDENTICAL k-iter counts
// (g+1) -> block-uniform runtime; g mapped descending so long blocks launch
// first. NO launch_bounds wave cap (lesson of r8/r9: caps -> 64 VGPR ->
// scratch spill). Direct-global K/V B-operand fragments (L2-served,
// XCD-affinity swizzle). Only LDS: wave-private P round-trip, no barriers.
// ---------------------------------------------------------------------------
__global__ __launch_bounds__(128) void attn(
    const bf16_t* __restrict__ Q, const bf16_t* __restrict__ Kt,
    const bf16_t* __restrict__ Vt, bf16_t* __restrict__ O)
{
    const int tid  = threadIdx.x;
    const int w    = tid >> 6;            // wave in block (0/1)
    const int lane = tid & 63;
    const int quad = lane >> 4;
    const int l16  = lane & 15;

    __shared__ alignas(16) bf16_t lPall[2 * 32 * LSTR];  // 9.2 KiB
    bf16_t* lP = &lPall[w * 32 * LSTR];

    // XCD-affinity decode: all blocks of a given bh land on XCD bh&7.
    const int blk  = blockIdx.x;          // 0..2047
    const int xcd  = blk & 7;
    const int rest = blk >> 3;            // 0..255
    const int g    = 31 - (rest & 31);    // descending: long blocks first
    const int bh   = (rest >> 5) * 8 + xcd;
    const int t    = g * 2 + w;           // this wave's 32-row tile (0..63)

    const float sscale = 0.125f * 1.44269504088896f;  // 1/sqrt(64)*log2(e)
    const int b = bh >> 4, h = bh & 15;
    unsigned short* Ou = (unsigned short*)O;
    const bf16_t* Kb = Kt + (size_t)bh * SS * HDD;
    const bf16_t* Vb = Vt + (size_t)bh * HDD * SS;

    const int q0  = t * 32;
    const int nkb = (t >> 1) + 1;

    // Q fragments: 2 subtiles x 2 k-chunks, straight from global
    bf16x8 qf[2][2];
#pragma unroll
    for (int qs = 0; qs < 2; ++qs) {
        const bf16_t* qp =
            Q + (size_t)(bh * SS + q0 + qs * 16 + l16) * HDD + quad * 8;
        qf[qs][0] = *(const bf16x8*)(qp);
        qf[qs][1] = *(const bf16x8*)(qp + 32);
    }

    f32x4 o[2][4];
    float ps[2][4];
#pragma unroll
    for (int qs = 0; qs < 2; ++qs)
#pragma unroll
        for (int i = 0; i < 4; ++i) {
            o[qs][i] = (f32x4){0.f, 0.f, 0.f, 0.f};
            ps[qs][i] = 0.f;
        }

    for (int ib = 0; ib < nkb; ++ib) {
        const int kb = ib * 64;
        const bool diag = (ib == nkb - 1);

        // K fragments (B-operand), direct global loads
        bf16x8 kf[4][2];
#pragma unroll
        for (int nt = 0; nt < 4; ++nt) {
            const bf16_t* kp =
                Kb + (size_t)(kb + nt * 16 + l16) * HDD + quad * 8;
            kf[nt][0] = *(const bf16x8*)(kp);
            kf[nt][1] = *(const bf16x8*)(kp + 32);
        }
        // V fragments (B-operand), independent of P -> issue early
        bf16x8 vf[2][4];
#pragma unroll
        for (int kk = 0; kk < 2; ++kk)
#pragma unroll
            for (int nt = 0; nt < 4; ++nt)
                vf[kk][nt] = *(const bf16x8*)
                    &Vb[(size_t)(nt * 16 + l16) * SS + kb + kk * 32 + quad * 8];

        // scores + exp + packed P write
#pragma unroll
        for (int nt = 0; nt < 4; ++nt) {
            int colg = kb + nt * 16 + l16;
#pragma unroll
            for (int qs = 0; qs < 2; ++qs) {
                f32x4 s = (f32x4){0.f, 0.f, 0.f, 0.f};
                s = __builtin_amdgcn_mfma_f32_16x16x32_bf16(
                    qf[qs][0], kf[nt][0], s, 0, 0, 0);
                s = __builtin_amdgcn_mfma_f32_16x16x32_bf16(
                    qf[qs][1], kf[nt][1], s, 0, 0, 0);
                int rbase = q0 + qs * 16 + quad * 4;
#pragma unroll
                for (int r = 0; r < 4; ++r) {
                    float sv = s[r];
                    if (diag && colg > rbase + r) sv = -1e30f;
                    float pv = exp2f(sv * sscale);
                    ps[qs][r] += pv;
                    float partner = __shfl_xor(pv, 1);
                    if ((lane & 1) == 0) {
                        // truncating bf16 pack
                        unsigned pk = (__float_as_uint(pv) >> 16) |
                                      (__float_as_uint(partner) & 0xFFFF0000u);
                        int row = qs * 16 + quad * 4 + r;
                        *(unsigned*)&lP[row * LSTR + nt * 16 + l16] = pk;
                    }
                }
            }
        }

        // PV: O += P @ V  (wave-private LDS RAW; per-wave DS in-order)
#pragma unroll
        for (int kk = 0; kk < 2; ++kk) {
            bf16x8 pf[2];
#pragma unroll
            for (int qs = 0; qs < 2; ++qs)
                pf[qs] = *(const bf16x8*)
                    &lP[(qs * 16 + l16) * LSTR + kk * 32 + quad * 8];
#pragma unroll
            for (int nt = 0; nt < 4; ++nt)
#pragma unroll
                for (int qs = 0; qs < 2; ++qs)
                    o[qs][nt] = __builtin_amdgcn_mfma_f32_16x16x32_bf16(
                        pf[qs], vf[kk][nt], o[qs][nt], 0, 0, 0);
        }
    }

    // epilogue: cross-lane row-sum reduce, O/l, write bf16 (B,S,D)
#pragma unroll
    for (int qs = 0; qs < 2; ++qs) {
        float lr[4];
#pragma unroll
        for (int r = 0; r < 4; ++r) {
            float v = ps[qs][r];
            v += __shfl_xor(v, 1);
            v += __shfl_xor(v, 2);
            v += __shfl_xor(v, 4);
            v += __shfl_xor(v, 8);
            lr[r] = v;
        }
#pragma unroll
        for (int nt = 0; nt < 4; ++nt) {
            int d = nt * 16 + l16;
#pragma unroll
            for (int r = 0; r < 4; ++r) {
                int s = q0 + qs * 16 + quad * 4 + r;
                float v = o[qs][nt][r] / lr[r];
                Ou[(size_t)(b * SS + s) * DD + h * HDD + d] = f2bf(v);
            }
        }
    }
}

// ---------------------------------------------------------------------------
// Buffer plan.  TSZ = B*S*D bf16 = 16 MiB; WSZ = D*D bf16 = 2 MiB.
//   d_out (32 MiB fp32): [0,TSZ) = xb, [TSZ,2*TSZ) = Vt — both dead before
//     gemm_out overwrites d_out (it reads only Ob, wb3).
//   ws: Qb | Kb | Ob | wb0..3 = 56 MiB.  wb0..2 contiguous => W3 for QKV.
// ---------------------------------------------------------------------------
extern "C" void kernel_launch(void* const* d_in, const int* in_sizes, int n_in,
                              void* d_out, int out_size, void* d_ws,
                              size_t ws_size, hipStream_t stream)
{
    const float* x    = (const float*)d_in[0];
    const float* fcos = (const float*)d_in[1];
    const float* fsin = (const float*)d_in[2];
    const float* wq   = (const float*)d_in[3];
    const float* wk   = (const float*)d_in[4];
    const float* wv   = (const float*)d_in[5];
    const float* wo   = (const float*)d_in[6];

    char* ws = (char*)d_ws;
    const size_t TSZ = (size_t)BB * SS * DD * sizeof(bf16_t);  // 16 MiB
    const size_t WSZ = (size_t)DD * DD * sizeof(bf16_t);       // 2 MiB
    bf16_t* Qb  = (bf16_t*)(ws);
    bf16_t* Kb  = (bf16_t*)(ws + TSZ);
    bf16_t* Ob  = (bf16_t*)(ws + 2 * TSZ);
    bf16_t* wb0 = (bf16_t*)(ws + 3 * TSZ);
    bf16_t* wb1 = (bf16_t*)(ws + 3 * TSZ + WSZ);
    bf16_t* wb2 = (bf16_t*)(ws + 3 * TSZ + 2 * WSZ);
    bf16_t* wb3 = (bf16_t*)(ws + 3 * TSZ + 3 * WSZ);
    bf16_t* xb  = (bf16_t*)d_out;
    bf16_t* Vt  = (bf16_t*)((char*)d_out + TSZ);

    dim3 bb(256);
    cvt1<<<dim3(4096), bb, 0, stream>>>(x, xb);
    cvt4<<<dim3(512, 4), bb, 0, stream>>>(wq, wk, wv, wo, wb0, wb1, wb2, wb3);

    gemm_qkv<<<dim3(24, 64), bb, 0, stream>>>(xb, wb0, Qb, Kb, Vt, fcos, fsin);
    attn<<<dim3(2048), dim3(128), 0, stream>>>(Qb, Kb, Vt, Ob);
    gemm_out<<<dim3(8, 64), bb, 0, stream>>>(Ob, wb3, (float*)d_out);
}

// Round 11
// 394.585 us; speedup vs baseline: 1.5922x; 1.0543x over previous
//
#include <hip/hip_runtime.h>
#include <hip/hip_bf16.h>
#include <cstdint>
#include <cstddef>

// Problem constants
#define BB 4
#define SS 2048
#define DD 1024
#define HH 16
#define HDD 64

typedef __bf16 bf16_t;
typedef __bf16 bf16x8 __attribute__((ext_vector_type(8)));
typedef float f32x4 __attribute__((ext_vector_type(4)));

__device__ __forceinline__ unsigned short f2bf(float f) {
    unsigned u = __float_as_uint(f);
    unsigned r = (u + 0x7FFFu + ((u >> 16) & 1u)) >> 16;
    return (unsigned short)r;
}
__device__ __forceinline__ bf16_t f2bf16(float f) {
    return __builtin_bit_cast(bf16_t, f2bf(f));
}
__device__ __forceinline__ bf16x8 cvt8(float4 a, float4 b) {
    bf16x8 r;
    r[0] = f2bf16(a.x); r[1] = f2bf16(a.y);
    r[2] = f2bf16(a.z); r[3] = f2bf16(a.w);
    r[4] = f2bf16(b.x); r[5] = f2bf16(b.y);
    r[6] = f2bf16(b.z); r[7] = f2bf16(b.w);
    return r;
}

// async global->LDS, 16B per lane; LDS dest = wave-uniform base + lane*16
#define GLL16(gp, lp)                                                          \
    __builtin_amdgcn_global_load_lds(                                          \
        (const __attribute__((address_space(1))) void*)(gp),                   \
        (__attribute__((address_space(3))) void*)(lp), 16, 0, 0)

// padded stride for attn P tile (72 elem = 144 B): 16B-aligned rows, <=2-way
// bank aliasing on both the packed b32 writes and the b128 reads (free).
#define LSTR 72

// 1/sqrt(64) * log2(e), folded into Q at projection time
#define QSCALE 0.18033688011112042f

// ---------------------------------------------------------------------------
// fp32 -> bf16 converters (memory-bound, one-shot)
// ---------------------------------------------------------------------------
__global__ __launch_bounds__(256) void cvt1(const float* __restrict__ in,
                                            bf16_t* __restrict__ out) {
    size_t i = (size_t)blockIdx.x * 256 + threadIdx.x;
    const float4* p = (const float4*)in + i * 2;
    *(bf16x8*)(out + i * 8) = cvt8(p[0], p[1]);
}
__global__ __launch_bounds__(256) void cvt4(
    const float* __restrict__ w0, const float* __restrict__ w1,
    const float* __restrict__ w2, const float* __restrict__ w3,
    bf16_t* __restrict__ o0, bf16_t* __restrict__ o1,
    bf16_t* __restrict__ o2, bf16_t* __restrict__ o3) {
    const float* in = blockIdx.y == 0 ? w0 : blockIdx.y == 1 ? w1
                    : blockIdx.y == 2 ? w2 : w3;
    bf16_t* out = blockIdx.y == 0 ? o0 : blockIdx.y == 1 ? o1
                : blockIdx.y == 2 ? o2 : o3;
    size_t i = (size_t)blockIdx.x * 256 + threadIdx.x;
    const float4* p = (const float4*)in + i * 2;
    *(bf16x8*)(out + i * 8) = cvt8(p[0], p[1]);
}

// ---------------------------------------------------------------------------
// Fused QKV GEMM: C(8192x3072) = x(8192x1024) @ W3^T, W3 = [wq;wk;wv] rows.
// Section (block-uniform, n0>>10): 0 -> Q rope*QSCALE (B,H,S,HD), 1 -> K rope,
// 2 -> V transposed (B,H,HD,S). m97-pattern GLL16 staging.
// ---------------------------------------------------------------------------
__global__ __launch_bounds__(256, 2) void gemm_qkv(
    const bf16_t* __restrict__ A, const bf16_t* __restrict__ W3,
    bf16_t* __restrict__ Qb, bf16_t* __restrict__ Kb, bf16_t* __restrict__ Vtb,
    const float* __restrict__ fcos, const float* __restrict__ fsin)
{
    constexpr int K = 1024;
    __shared__ alignas(16) bf16_t lA[128 * 64];
    __shared__ alignas(16) bf16_t lB[128 * 64];

    const int tid  = threadIdx.x;
    const int w    = tid >> 6;
    const int lane = tid & 63;
    const int quad = lane >> 4;
    const int l16  = lane & 15;
    const int wm   = w >> 1;
    const int wn   = w & 1;
    const int m0   = blockIdx.y * 128;
    const int n0   = blockIdx.x * 128;

    f32x4 acc[4][4];
#pragma unroll
    for (int i = 0; i < 4; i++)
#pragma unroll
        for (int j = 0; j < 4; j++) acc[i][j] = (f32x4){0.f, 0.f, 0.f, 0.f};

    const int srow8 = lane >> 3;
    const int slot  = lane & 7;

    for (int k0 = 0; k0 < K; k0 += 64) {
#pragma unroll
        for (int i = 0; i < 4; ++i) {
            int row = w * 32 + i * 8;
            GLL16(A + (size_t)(m0 + row + srow8) * K + k0 + slot * 8,
                  &lA[row * 64]);
            GLL16(W3 + (size_t)(n0 + row + srow8) * K + k0 + slot * 8,
                  &lB[row * 64]);
        }
        __syncthreads();
#pragma unroll
        for (int kk = 0; kk < 2; ++kk) {
            bf16x8 af[4], bfr[4];
#pragma unroll
            for (int mt = 0; mt < 4; ++mt)
                af[mt] = *(const bf16x8*)
                    &lA[(wm * 64 + mt * 16 + l16) * 64 + (kk * 4 + quad) * 8];
#pragma unroll
            for (int nt = 0; nt < 4; ++nt)
                bfr[nt] = *(const bf16x8*)
                    &lB[(wn * 64 + nt * 16 + l16) * 64 + (kk * 4 + quad) * 8];
#pragma unroll
            for (int mt = 0; mt < 4; ++mt)
#pragma unroll
                for (int nt = 0; nt < 4; ++nt)
                    acc[mt][nt] = __builtin_amdgcn_mfma_f32_16x16x32_bf16(
                        af[mt], bfr[nt], acc[mt][nt], 0, 0, 0);
        }
        __syncthreads();
    }

    const int sect = n0 >> 10;  // 0=Q,1=K,2=V (uniform per block)
    if (sect < 2) {
        unsigned short* Cu = (unsigned short*)(sect ? Kb : Qb);
        const float osc = sect ? 1.0f : QSCALE;
#pragma unroll
        for (int mt = 0; mt < 4; ++mt) {
#pragma unroll
            for (int nt = 0; nt < 4; ++nt) {
                int col  = n0 + wn * 64 + nt * 16 + l16;
                int h    = (col >> 6) & 15;
                int d    = col & 63;
                int pidx = d >> 1;
                bool even = (col & 1) == 0;
#pragma unroll
                for (int r = 0; r < 4; ++r) {
                    int m = m0 + wm * 64 + mt * 16 + quad * 4 + r;
                    int b = m >> 11;   // / S
                    int s = m & 2047;  // % S
                    float v  = acc[mt][nt][r];
                    float p  = __shfl_xor(v, 1);
                    float c  = fcos[s * 32 + pidx];
                    float sn = fsin[s * 32 + pidx];
                    float o  = (even ? (v * c - p * sn) : (p * sn + v * c)) * osc;
                    float po = __shfl_xor(o, 1);  // partner's rotated value
                    if (even) {
                        unsigned pk = (unsigned)f2bf(o) |
                                      ((unsigned)f2bf(po) << 16);
                        *(unsigned*)&Cu[(size_t)((b * HH + h) * SS + s) * HDD + d] = pk;
                    }
                }
            }
        }
    } else {
        unsigned short* Cu = (unsigned short*)Vtb;
#pragma unroll
        for (int mt = 0; mt < 4; ++mt) {
#pragma unroll
            for (int nt = 0; nt < 4; ++nt) {
                int col = n0 + wn * 64 + nt * 16 + l16;
                int h = (col >> 6) & 15, d = col & 63;
#pragma unroll
                for (int r = 0; r < 4; ++r) {
                    int m = m0 + wm * 64 + mt * 16 + quad * 4 + r;
                    int b = m >> 11, s = m & 2047;
                    Cu[(size_t)((b * HH + h) * HDD + d) * SS + s] =
                        f2bf(acc[mt][nt][r]);
                }
            }
        }
    }
}

// ---------------------------------------------------------------------------
// Out-projection GEMM: d_out(8192x1024 fp32) = Ob(bf16) @ wo^T(bf16).
// ---------------------------------------------------------------------------
__global__ __launch_bounds__(256, 2) void gemm_out(
    const bf16_t* __restrict__ A, const bf16_t* __restrict__ W,
    float* __restrict__ Cf)
{
    constexpr int K = 1024, N = 1024;
    __shared__ alignas(16) bf16_t lA[128 * 64];
    __shared__ alignas(16) bf16_t lB[128 * 64];

    const int tid  = threadIdx.x;
    const int w    = tid >> 6;
    const int lane = tid & 63;
    const int quad = lane >> 4;
    const int l16  = lane & 15;
    const int wm   = w >> 1;
    const int wn   = w & 1;
    const int m0   = blockIdx.y * 128;
    const int n0   = blockIdx.x * 128;

    f32x4 acc[4][4];
#pragma unroll
    for (int i = 0; i < 4; i++)
#pragma unroll
        for (int j = 0; j < 4; j++) acc[i][j] = (f32x4){0.f, 0.f, 0.f, 0.f};

    const int srow8 = lane >> 3;
    const int slot  = lane & 7;

    for (int k0 = 0; k0 < K; k0 += 64) {
#pragma unroll
        for (int i = 0; i < 4; ++i) {
            int row = w * 32 + i * 8;
            GLL16(A + (size_t)(m0 + row + srow8) * K + k0 + slot * 8,
                  &lA[row * 64]);
            GLL16(W + (size_t)(n0 + row + srow8) * K + k0 + slot * 8,
                  &lB[row * 64]);
        }
        __syncthreads();
#pragma unroll
        for (int kk = 0; kk < 2; ++kk) {
            bf16x8 af[4], bfr[4];
#pragma unroll
            for (int mt = 0; mt < 4; ++mt)
                af[mt] = *(const bf16x8*)
                    &lA[(wm * 64 + mt * 16 + l16) * 64 + (kk * 4 + quad) * 8];
#pragma unroll
            for (int nt = 0; nt < 4; ++nt)
                bfr[nt] = *(const bf16x8*)
                    &lB[(wn * 64 + nt * 16 + l16) * 64 + (kk * 4 + quad) * 8];
#pragma unroll
            for (int mt = 0; mt < 4; ++mt)
#pragma unroll
                for (int nt = 0; nt < 4; ++nt)
                    acc[mt][nt] = __builtin_amdgcn_mfma_f32_16x16x32_bf16(
                        af[mt], bfr[nt], acc[mt][nt], 0, 0, 0);
        }
        __syncthreads();
    }

#pragma unroll
    for (int mt = 0; mt < 4; ++mt) {
        int mrow = m0 + wm * 64 + mt * 16 + quad * 4;
#pragma unroll
        for (int nt = 0; nt < 4; ++nt) {
            int col = n0 + wn * 64 + nt * 16 + l16;
#pragma unroll
            for (int r = 0; r < 4; ++r)
                Cf[(size_t)(mrow + r) * N + col] = acc[mt][nt][r];
        }
    }
}

// ---------------------------------------------------------------------------
// Flash attention v7 — k-parity wave split, balanced & resident.
// Q (pre-scaled by QSCALE), K (B,H,S,HD); Vt (B,H,HD,S); O (B,S,D).
// Each block (128 thr = 2 waves) owns one tile-pair (pg, 63-pg) of 32-row
// q-tiles; wave w processes k-blocks of parity w. Pair totals 33 k-iters ->
// wave0 = 17, wave1 = 16, every block identical. 2048 blocks x 2 waves =
// 4096 waves = 16/CU, all resident (r10 lesson: balance the CU assignment;
// r8/r9 lesson: no launch_bounds wave cap -> no spill). No-max softmax
// partials combine linearly via LDS once per tile (barriers outside K-loop).
// Direct-global K/V B-operand fragments (L2-served, XCD-affinity swizzle);
// wave-private LDS P round-trip inside the loop, barrier-free.
// ---------------------------------------------------------------------------
__global__ __launch_bounds__(128) void attn(
    const bf16_t* __restrict__ Q, const bf16_t* __restrict__ Kt,
    const bf16_t* __restrict__ Vt, bf16_t* __restrict__ O)
{
    const int tid  = threadIdx.x;
    const int w    = tid >> 6;            // wave in block = k-parity
    const int lane = tid & 63;
    const int quad = lane >> 4;
    const int l16  = lane & 15;

    __shared__ alignas(16) bf16_t lPall[2 * 32 * LSTR];  // 9.2 KiB
    __shared__ alignas(16) float comb[2560];             // 10 KiB
    bf16_t* lP = &lPall[w * 32 * LSTR];

    // XCD-affinity decode: all blocks of a given bh land on XCD bh&7.
    const int blk  = blockIdx.x;          // 0..2047
    const int xcd  = blk & 7;
    const int rest = blk >> 3;            // 0..255
    const int pg   = rest & 31;           // pair index 0..31
    const int bh   = (rest >> 5) * 8 + xcd;

    const int b = bh >> 4, h = bh & 15;
    unsigned short* Ou = (unsigned short*)O;
    const bf16_t* Kb = Kt + (size_t)bh * SS * HDD;
    const bf16_t* Vb = Vt + (size_t)bh * HDD * SS;

    for (int half = 0; half < 2; ++half) {
        const int t   = half ? 63 - pg : pg;   // 32-row tile index
        const int q0  = t * 32;
        const int nkb = (t >> 1) + 1;

        // Q fragments: 2 subtiles x 2 k-chunks, straight from global
        bf16x8 qf[2][2];
#pragma unroll
        for (int qs = 0; qs < 2; ++qs) {
            const bf16_t* qp =
                Q + (size_t)(bh * SS + q0 + qs * 16 + l16) * HDD + quad * 8;
            qf[qs][0] = *(const bf16x8*)(qp);
            qf[qs][1] = *(const bf16x8*)(qp + 32);
        }

        f32x4 o[2][4];
        float ps[2][4];
#pragma unroll
        for (int qs = 0; qs < 2; ++qs)
#pragma unroll
            for (int i = 0; i < 4; ++i) {
                o[qs][i] = (f32x4){0.f, 0.f, 0.f, 0.f};
                ps[qs][i] = 0.f;
            }

        for (int ib = w; ib < nkb; ib += 2) {
            const int kb = ib * 64;
            const bool diag = (ib == nkb - 1);

            // K fragments (B-operand), direct global loads
            bf16x8 kf[4][2];
#pragma unroll
            for (int nt = 0; nt < 4; ++nt) {
                const bf16_t* kp =
                    Kb + (size_t)(kb + nt * 16 + l16) * HDD + quad * 8;
                kf[nt][0] = *(const bf16x8*)(kp);
                kf[nt][1] = *(const bf16x8*)(kp + 32);
            }
            // V fragments (B-operand), independent of P -> issue early
            bf16x8 vf[2][4];
#pragma unroll
            for (int kk = 0; kk < 2; ++kk)
#pragma unroll
                for (int nt = 0; nt < 4; ++nt)
                    vf[kk][nt] = *(const bf16x8*)
                        &Vb[(size_t)(nt * 16 + l16) * SS + kb + kk * 32 + quad * 8];

            // scores + exp + packed P write (Q pre-scaled: exp2 direct)
#pragma unroll
            for (int nt = 0; nt < 4; ++nt) {
                int colg = kb + nt * 16 + l16;
#pragma unroll
                for (int qs = 0; qs < 2; ++qs) {
                    f32x4 s = (f32x4){0.f, 0.f, 0.f, 0.f};
                    s = __builtin_amdgcn_mfma_f32_16x16x32_bf16(
                        qf[qs][0], kf[nt][0], s, 0, 0, 0);
                    s = __builtin_amdgcn_mfma_f32_16x16x32_bf16(
                        qf[qs][1], kf[nt][1], s, 0, 0, 0);
                    int rbase = q0 + qs * 16 + quad * 4;
#pragma unroll
                    for (int r = 0; r < 4; ++r) {
                        float sv = s[r];
                        if (diag && colg > rbase + r) sv = -1e30f;
                        float pv = exp2f(sv);
                        ps[qs][r] += pv;
                        float partner = __shfl_xor(pv, 1);
                        if ((lane & 1) == 0) {
                            // truncating bf16 pack
                            unsigned pk = (__float_as_uint(pv) >> 16) |
                                          (__float_as_uint(partner) & 0xFFFF0000u);
                            int row = qs * 16 + quad * 4 + r;
                            *(unsigned*)&lP[row * LSTR + nt * 16 + l16] = pk;
                        }
                    }
                }
            }

            // PV: O += P @ V  (wave-private LDS RAW; per-wave DS in-order)
#pragma unroll
            for (int kk = 0; kk < 2; ++kk) {
                bf16x8 pf[2];
#pragma unroll
                for (int qs = 0; qs < 2; ++qs)
                    pf[qs] = *(const bf16x8*)
                        &lP[(qs * 16 + l16) * LSTR + kk * 32 + quad * 8];
#pragma unroll
                for (int nt = 0; nt < 4; ++nt)
#pragma unroll
                    for (int qs = 0; qs < 2; ++qs)
                        o[qs][nt] = __builtin_amdgcn_mfma_f32_16x16x32_bf16(
                            pf[qs], vf[kk][nt], o[qs][nt], 0, 0, 0);
            }
        }

        // combine parity partials (linear: no-max softmax), wave0 writes out
        __syncthreads();
        if (w == 1) {
#pragma unroll
            for (int qs = 0; qs < 2; ++qs)
#pragma unroll
                for (int nt = 0; nt < 4; ++nt)
#pragma unroll
                    for (int j = 0; j < 4; ++j)
                        comb[(qs * 4 + nt) * 256 + j * 64 + lane] = o[qs][nt][j];
#pragma unroll
            for (int qs = 0; qs < 2; ++qs)
#pragma unroll
                for (int r = 0; r < 4; ++r)
                    comb[2048 + (qs * 4 + r) * 64 + lane] = ps[qs][r];
        }
        __syncthreads();
        if (w == 0) {
#pragma unroll
            for (int qs = 0; qs < 2; ++qs)
#pragma unroll
                for (int nt = 0; nt < 4; ++nt)
#pragma unroll
                    for (int j = 0; j < 4; ++j)
                        o[qs][nt][j] += comb[(qs * 4 + nt) * 256 + j * 64 + lane];
#pragma unroll
            for (int qs = 0; qs < 2; ++qs) {
                float lr[4];
#pragma unroll
                for (int r = 0; r < 4; ++r) {
                    float v = ps[qs][r] + comb[2048 + (qs * 4 + r) * 64 + lane];
                    v += __shfl_xor(v, 1);
                    v += __shfl_xor(v, 2);
                    v += __shfl_xor(v, 4);
                    v += __shfl_xor(v, 8);
                    lr[r] = __builtin_amdgcn_rcpf(v);
                }
#pragma unroll
                for (int nt = 0; nt < 4; ++nt) {
                    int d = nt * 16 + l16;
#pragma unroll
                    for (int r = 0; r < 4; ++r) {
                        int s = q0 + qs * 16 + quad * 4 + r;
                        float v = o[qs][nt][r] * lr[r];
                        Ou[(size_t)(b * SS + s) * DD + h * HDD + d] = f2bf(v);
                    }
                }
            }
        }
    }
}

// ---------------------------------------------------------------------------
// Buffer plan.  TSZ = B*S*D bf16 = 16 MiB; WSZ = D*D bf16 = 2 MiB.
//   d_out (32 MiB fp32): [0,TSZ) = xb, [TSZ,2*TSZ) = Vt — both dead before
//     gemm_out overwrites d_out (it reads only Ob, wb3).
//   ws: Qb | Kb | Ob | wb0..3 = 56 MiB.  wb0..2 contiguous => W3 for QKV.
// ---------------------------------------------------------------------------
extern "C" void kernel_launch(void* const* d_in, const int* in_sizes, int n_in,
                              void* d_out, int out_size, void* d_ws,
                              size_t ws_size, hipStream_t stream)
{
    const float* x    = (const float*)d_in[0];
    const float* fcos = (const float*)d_in[1];
    const float* fsin = (const float*)d_in[2];
    const float* wq   = (const float*)d_in[3];
    const float* wk   = (const float*)d_in[4];
    const float* wv   = (const float*)d_in[5];
    const float* wo   = (const float*)d_in[6];

    char* ws = (char*)d_ws;
    const size_t TSZ = (size_t)BB * SS * DD * sizeof(bf16_t);  // 16 MiB
    const size_t WSZ = (size_t)DD * DD * sizeof(bf16_t);       // 2 MiB
    bf16_t* Qb  = (bf16_t*)(ws);
    bf16_t* Kb  = (bf16_t*)(ws + TSZ);
    bf16_t* Ob  = (bf16_t*)(ws + 2 * TSZ);
    bf16_t* wb0 = (bf16_t*)(ws + 3 * TSZ);
    bf16_t* wb1 = (bf16_t*)(ws + 3 * TSZ + WSZ);
    bf16_t* wb2 = (bf16_t*)(ws + 3 * TSZ + 2 * WSZ);
    bf16_t* wb3 = (bf16_t*)(ws + 3 * TSZ + 3 * WSZ);
    bf16_t* xb  = (bf16_t*)d_out;
    bf16_t* Vt  = (bf16_t*)((char*)d_out + TSZ);

    dim3 bb(256);
    cvt1<<<dim3(4096), bb, 0, stream>>>(x, xb);
    cvt4<<<dim3(512, 4), bb, 0, stream>>>(wq, wk, wv, wo, wb0, wb1, wb2, wb3);

    gemm_qkv<<<dim3(24, 64), bb, 0, stream>>>(xb, wb0, Qb, Kb, Vt, fcos, fsin);
    attn<<<dim3(2048), dim3(128), 0, stream>>>(Qb, Kb, Vt, Ob);
    gemm_out<<<dim3(8, 64), bb, 0, stream>>>(Ob, wb3, (float*)d_out);
}

// Round 12
// 371.768 us; speedup vs baseline: 1.6899x; 1.0614x over previous
//
#include <hip/hip_runtime.h>
#include <hip/hip_bf16.h>
#include <cstdint>
#include <cstddef>

// Problem constants
#define BB 4
#define SS 2048
#define DD 1024
#define HH 16
#define HDD 64

typedef __bf16 bf16_t;
typedef __bf16 bf16x8 __attribute__((ext_vector_type(8)));
typedef float f32x4 __attribute__((ext_vector_type(4)));

__device__ __forceinline__ unsigned short f2bf(float f) {
    unsigned u = __float_as_uint(f);
    unsigned r = (u + 0x7FFFu + ((u >> 16) & 1u)) >> 16;
    return (unsigned short)r;
}
__device__ __forceinline__ bf16_t f2bf16(float f) {
    return __builtin_bit_cast(bf16_t, f2bf(f));
}
__device__ __forceinline__ bf16x8 cvt8(float4 a, float4 b) {
    bf16x8 r;
    r[0] = f2bf16(a.x); r[1] = f2bf16(a.y);
    r[2] = f2bf16(a.z); r[3] = f2bf16(a.w);
    r[4] = f2bf16(b.x); r[5] = f2bf16(b.y);
    r[6] = f2bf16(b.z); r[7] = f2bf16(b.w);
    return r;
}

// async global->LDS, 16B per lane; LDS dest = wave-uniform base + lane*16
#define GLL16(gp, lp)                                                          \
    __builtin_amdgcn_global_load_lds(                                          \
        (const __attribute__((address_space(1))) void*)(gp),                   \
        (__attribute__((address_space(3))) void*)(lp), 16, 0, 0)

// padded stride for attn P tile (72 elem = 144 B): 16B-aligned rows, <=2-way
// bank aliasing on both the packed b32 writes and the b128 reads (free).
#define LSTR 72

// 1/sqrt(64) * log2(e), folded into Q at projection time
#define QSCALE 0.18033688011112042f

// ---------------------------------------------------------------------------
// fp32 -> bf16 converters (memory-bound, one-shot)
// ---------------------------------------------------------------------------
__global__ __launch_bounds__(256) void cvt1(const float* __restrict__ in,
                                            bf16_t* __restrict__ out) {
    size_t i = (size_t)blockIdx.x * 256 + threadIdx.x;
    const float4* p = (const float4*)in + i * 2;
    *(bf16x8*)(out + i * 8) = cvt8(p[0], p[1]);
}
__global__ __launch_bounds__(256) void cvt4(
    const float* __restrict__ w0, const float* __restrict__ w1,
    const float* __restrict__ w2, const float* __restrict__ w3,
    bf16_t* __restrict__ o0, bf16_t* __restrict__ o1,
    bf16_t* __restrict__ o2, bf16_t* __restrict__ o3) {
    const float* in = blockIdx.y == 0 ? w0 : blockIdx.y == 1 ? w1
                    : blockIdx.y == 2 ? w2 : w3;
    bf16_t* out = blockIdx.y == 0 ? o0 : blockIdx.y == 1 ? o1
                : blockIdx.y == 2 ? o2 : o3;
    size_t i = (size_t)blockIdx.x * 256 + threadIdx.x;
    const float4* p = (const float4*)in + i * 2;
    *(bf16x8*)(out + i * 8) = cvt8(p[0], p[1]);
}

// ---------------------------------------------------------------------------
// Fused QKV GEMM: C(8192x3072) = x(8192x1024) @ W3^T, W3 = [wq;wk;wv] rows.
// Section (block-uniform, n0>>10): 0 -> Q rope*QSCALE (B,H,S,HD), 1 -> K rope,
// 2 -> V transposed (B,H,HD,S). m97-pattern GLL16 staging.
// ---------------------------------------------------------------------------
__global__ __launch_bounds__(256, 2) void gemm_qkv(
    const bf16_t* __restrict__ A, const bf16_t* __restrict__ W3,
    bf16_t* __restrict__ Qb, bf16_t* __restrict__ Kb, bf16_t* __restrict__ Vtb,
    const float* __restrict__ fcos, const float* __restrict__ fsin)
{
    constexpr int K = 1024;
    __shared__ alignas(16) bf16_t lA[128 * 64];
    __shared__ alignas(16) bf16_t lB[128 * 64];

    const int tid  = threadIdx.x;
    const int w    = tid >> 6;
    const int lane = tid & 63;
    const int quad = lane >> 4;
    const int l16  = lane & 15;
    const int wm   = w >> 1;
    const int wn   = w & 1;
    const int m0   = blockIdx.y * 128;
    const int n0   = blockIdx.x * 128;

    f32x4 acc[4][4];
#pragma unroll
    for (int i = 0; i < 4; i++)
#pragma unroll
        for (int j = 0; j < 4; j++) acc[i][j] = (f32x4){0.f, 0.f, 0.f, 0.f};

    const int srow8 = lane >> 3;
    const int slot  = lane & 7;

    for (int k0 = 0; k0 < K; k0 += 64) {
#pragma unroll
        for (int i = 0; i < 4; ++i) {
            int row = w * 32 + i * 8;
            GLL16(A + (size_t)(m0 + row + srow8) * K + k0 + slot * 8,
                  &lA[row * 64]);
            GLL16(W3 + (size_t)(n0 + row + srow8) * K + k0 + slot * 8,
                  &lB[row * 64]);
        }
        __syncthreads();
#pragma unroll
        for (int kk = 0; kk < 2; ++kk) {
            bf16x8 af[4], bfr[4];
#pragma unroll
            for (int mt = 0; mt < 4; ++mt)
                af[mt] = *(const bf16x8*)
                    &lA[(wm * 64 + mt * 16 + l16) * 64 + (kk * 4 + quad) * 8];
#pragma unroll
            for (int nt = 0; nt < 4; ++nt)
                bfr[nt] = *(const bf16x8*)
                    &lB[(wn * 64 + nt * 16 + l16) * 64 + (kk * 4 + quad) * 8];
#pragma unroll
            for (int mt = 0; mt < 4; ++mt)
#pragma unroll
                for (int nt = 0; nt < 4; ++nt)
                    acc[mt][nt] = __builtin_amdgcn_mfma_f32_16x16x32_bf16(
                        af[mt], bfr[nt], acc[mt][nt], 0, 0, 0);
        }
        __syncthreads();
    }

    const int sect = n0 >> 10;  // 0=Q,1=K,2=V (uniform per block)
    if (sect < 2) {
        unsigned short* Cu = (unsigned short*)(sect ? Kb : Qb);
        const float osc = sect ? 1.0f : QSCALE;
#pragma unroll
        for (int mt = 0; mt < 4; ++mt) {
#pragma unroll
            for (int nt = 0; nt < 4; ++nt) {
                int col  = n0 + wn * 64 + nt * 16 + l16;
                int h    = (col >> 6) & 15;
                int d    = col & 63;
                int pidx = d >> 1;
                bool even = (col & 1) == 0;
#pragma unroll
                for (int r = 0; r < 4; ++r) {
                    int m = m0 + wm * 64 + mt * 16 + quad * 4 + r;
                    int b = m >> 11;   // / S
                    int s = m & 2047;  // % S
                    float v  = acc[mt][nt][r];
                    float p  = __shfl_xor(v, 1);
                    float c  = fcos[s * 32 + pidx];
                    float sn = fsin[s * 32 + pidx];
                    float o  = (even ? (v * c - p * sn) : (p * sn + v * c)) * osc;
                    float po = __shfl_xor(o, 1);  // partner's rotated value
                    if (even) {
                        unsigned pk = (unsigned)f2bf(o) |
                                      ((unsigned)f2bf(po) << 16);
                        *(unsigned*)&Cu[(size_t)((b * HH + h) * SS + s) * HDD + d] = pk;
                    }
                }
            }
        }
    } else {
        unsigned short* Cu = (unsigned short*)Vtb;
#pragma unroll
        for (int mt = 0; mt < 4; ++mt) {
#pragma unroll
            for (int nt = 0; nt < 4; ++nt) {
                int col = n0 + wn * 64 + nt * 16 + l16;
                int h = (col >> 6) & 15, d = col & 63;
#pragma unroll
                for (int r = 0; r < 4; ++r) {
                    int m = m0 + wm * 64 + mt * 16 + quad * 4 + r;
                    int b = m >> 11, s = m & 2047;
                    Cu[(size_t)((b * HH + h) * HDD + d) * SS + s] =
                        f2bf(acc[mt][nt][r]);
                }
            }
        }
    }
}

// ---------------------------------------------------------------------------
// Out-projection GEMM: d_out(8192x1024 fp32) = Ob(bf16) @ wo^T(bf16).
// ---------------------------------------------------------------------------
__global__ __launch_bounds__(256, 2) void gemm_out(
    const bf16_t* __restrict__ A, const bf16_t* __restrict__ W,
    float* __restrict__ Cf)
{
    constexpr int K = 1024, N = 1024;
    __shared__ alignas(16) bf16_t lA[128 * 64];
    __shared__ alignas(16) bf16_t lB[128 * 64];

    const int tid  = threadIdx.x;
    const int w    = tid >> 6;
    const int lane = tid & 63;
    const int quad = lane >> 4;
    const int l16  = lane & 15;
    const int wm   = w >> 1;
    const int wn   = w & 1;
    const int m0   = blockIdx.y * 128;
    const int n0   = blockIdx.x * 128;

    f32x4 acc[4][4];
#pragma unroll
    for (int i = 0; i < 4; i++)
#pragma unroll
        for (int j = 0; j < 4; j++) acc[i][j] = (f32x4){0.f, 0.f, 0.f, 0.f};

    const int srow8 = lane >> 3;
    const int slot  = lane & 7;

    for (int k0 = 0; k0 < K; k0 += 64) {
#pragma unroll
        for (int i = 0; i < 4; ++i) {
            int row = w * 32 + i * 8;
            GLL16(A + (size_t)(m0 + row + srow8) * K + k0 + slot * 8,
                  &lA[row * 64]);
            GLL16(W + (size_t)(n0 + row + srow8) * K + k0 + slot * 8,
                  &lB[row * 64]);
        }
        __syncthreads();
#pragma unroll
        for (int kk = 0; kk < 2; ++kk) {
            bf16x8 af[4], bfr[4];
#pragma unroll
            for (int mt = 0; mt < 4; ++mt)
                af[mt] = *(const bf16x8*)
                    &lA[(wm * 64 + mt * 16 + l16) * 64 + (kk * 4 + quad) * 8];
#pragma unroll
            for (int nt = 0; nt < 4; ++nt)
                bfr[nt] = *(const bf16x8*)
                    &lB[(wn * 64 + nt * 16 + l16) * 64 + (kk * 4 + quad) * 8];
#pragma unroll
            for (int mt = 0; mt < 4; ++mt)
#pragma unroll
                for (int nt = 0; nt < 4; ++nt)
                    acc[mt][nt] = __builtin_amdgcn_mfma_f32_16x16x32_bf16(
                        af[mt], bfr[nt], acc[mt][nt], 0, 0, 0);
        }
        __syncthreads();
    }

#pragma unroll
    for (int mt = 0; mt < 4; ++mt) {
        int mrow = m0 + wm * 64 + mt * 16 + quad * 4;
#pragma unroll
        for (int nt = 0; nt < 4; ++nt) {
            int col = n0 + wn * 64 + nt * 16 + l16;
#pragma unroll
            for (int r = 0; r < 4; ++r)
                Cf[(size_t)(mrow + r) * N + col] = acc[mt][nt][r];
        }
    }
}

// ---------------------------------------------------------------------------
// Flash attention v8 — barrier-free, one 32-row tile per wave, PER-CU
// BALANCED mapping. HW block->CU mapping (observed r10): XCD = blk&7,
// CU slot = (blk>>3)&31, round = blk>>8. Decode:
//   s = CU slot: i = s&7 selects this CU's bh (= xcd + 8*i, so all 8 blocks
//   on a CU share one bh's K/V -> L1/L2 reuse); j = s>>3.
//   round r = 2u+p: g = p ? 31-(u*4+j) : u*4+j  -> four (g,31-g) pairs per
//   CU => exactly 264 wave-iters per CU, all 256 CUs identical.
// Block = 128 thr = 2 waves on tiles (2g, 2g+1), both nkb = g+1 (uniform).
// 4096 waves = 16/CU, all resident (92 VGPR -> 4/SIMD, LDS 9.2 KB).
// No launch_bounds cap (r8/r9: caps spill). Q pre-scaled by QSCALE.
// ---------------------------------------------------------------------------
__global__ __launch_bounds__(128) void attn(
    const bf16_t* __restrict__ Q, const bf16_t* __restrict__ Kt,
    const bf16_t* __restrict__ Vt, bf16_t* __restrict__ O)
{
    const int tid  = threadIdx.x;
    const int w    = tid >> 6;            // wave in block (0/1)
    const int lane = tid & 63;
    const int quad = lane >> 4;
    const int l16  = lane & 15;

    __shared__ alignas(16) bf16_t lPall[2 * 32 * LSTR];  // 9.2 KiB
    bf16_t* lP = &lPall[w * 32 * LSTR];

    // balanced decode (see header comment)
    const int blk = blockIdx.x;           // 0..2047
    const int xcd = blk & 7;
    const int s_  = (blk >> 3) & 31;      // CU slot within XCD
    const int r_  = blk >> 8;             // round 0..7
    const int i_  = s_ & 7;
    const int j_  = s_ >> 3;              // 0..3
    const int u_  = r_ >> 1;              // 0..3
    const int p_  = r_ & 1;
    const int base = u_ * 4 + j_;         // 0..15
    const int g   = p_ ? 31 - base : base;
    const int bh  = xcd + 8 * i_;
    const int t   = g * 2 + w;            // this wave's 32-row tile (0..63)

    const int b = bh >> 4, h = bh & 15;
    unsigned short* Ou = (unsigned short*)O;
    const bf16_t* Kb = Kt + (size_t)bh * SS * HDD;
    const bf16_t* Vb = Vt + (size_t)bh * HDD * SS;

    const int q0  = t * 32;
    const int nkb = (t >> 1) + 1;         // = g+1 for both waves

    // Q fragments: 2 subtiles x 2 k-chunks, straight from global
    bf16x8 qf[2][2];
#pragma unroll
    for (int qs = 0; qs < 2; ++qs) {
        const bf16_t* qp =
            Q + (size_t)(bh * SS + q0 + qs * 16 + l16) * HDD + quad * 8;
        qf[qs][0] = *(const bf16x8*)(qp);
        qf[qs][1] = *(const bf16x8*)(qp + 32);
    }

    f32x4 o[2][4];
    float ps[2][4];
#pragma unroll
    for (int qs = 0; qs < 2; ++qs)
#pragma unroll
        for (int i = 0; i < 4; ++i) {
            o[qs][i] = (f32x4){0.f, 0.f, 0.f, 0.f};
            ps[qs][i] = 0.f;
        }

    for (int ib = 0; ib < nkb; ++ib) {
        const int kb = ib * 64;
        const bool diag = (ib == nkb - 1);

        // K fragments (B-operand), direct global loads
        bf16x8 kf[4][2];
#pragma unroll
        for (int nt = 0; nt < 4; ++nt) {
            const bf16_t* kp =
                Kb + (size_t)(kb + nt * 16 + l16) * HDD + quad * 8;
            kf[nt][0] = *(const bf16x8*)(kp);
            kf[nt][1] = *(const bf16x8*)(kp + 32);
        }
        // V fragments (B-operand), independent of P -> issue early
        bf16x8 vf[2][4];
#pragma unroll
        for (int kk = 0; kk < 2; ++kk)
#pragma unroll
            for (int nt = 0; nt < 4; ++nt)
                vf[kk][nt] = *(const bf16x8*)
                    &Vb[(size_t)(nt * 16 + l16) * SS + kb + kk * 32 + quad * 8];

        // scores + exp + packed P write (Q pre-scaled: exp2 direct)
#pragma unroll
        for (int nt = 0; nt < 4; ++nt) {
            int colg = kb + nt * 16 + l16;
#pragma unroll
            for (int qs = 0; qs < 2; ++qs) {
                f32x4 s = (f32x4){0.f, 0.f, 0.f, 0.f};
                s = __builtin_amdgcn_mfma_f32_16x16x32_bf16(
                    qf[qs][0], kf[nt][0], s, 0, 0, 0);
                s = __builtin_amdgcn_mfma_f32_16x16x32_bf16(
                    qf[qs][1], kf[nt][1], s, 0, 0, 0);
                int rbase = q0 + qs * 16 + quad * 4;
#pragma unroll
                for (int r = 0; r < 4; ++r) {
                    float sv = s[r];
                    if (diag && colg > rbase + r) sv = -1e30f;
                    float pv = exp2f(sv);
                    ps[qs][r] += pv;
                    float partner = __shfl_xor(pv, 1);
                    if ((lane & 1) == 0) {
                        // truncating bf16 pack
                        unsigned pk = (__float_as_uint(pv) >> 16) |
                                      (__float_as_uint(partner) & 0xFFFF0000u);
                        int row = qs * 16 + quad * 4 + r;
                        *(unsigned*)&lP[row * LSTR + nt * 16 + l16] = pk;
                    }
                }
            }
        }

        // PV: O += P @ V  (wave-private LDS RAW; per-wave DS in-order)
#pragma unroll
        for (int kk = 0; kk < 2; ++kk) {
            bf16x8 pf[2];
#pragma unroll
            for (int qs = 0; qs < 2; ++qs)
                pf[qs] = *(const bf16x8*)
                    &lP[(qs * 16 + l16) * LSTR + kk * 32 + quad * 8];
#pragma unroll
            for (int nt = 0; nt < 4; ++nt)
#pragma unroll
                for (int qs = 0; qs < 2; ++qs)
                    o[qs][nt] = __builtin_amdgcn_mfma_f32_16x16x32_bf16(
                        pf[qs], vf[kk][nt], o[qs][nt], 0, 0, 0);
        }
    }

    // epilogue: cross-lane row-sum reduce, O * rcp(l), write bf16 (B,S,D)
#pragma unroll
    for (int qs = 0; qs < 2; ++qs) {
        float lr[4];
#pragma unroll
        for (int r = 0; r < 4; ++r) {
            float v = ps[qs][r];
            v += __shfl_xor(v, 1);
            v += __shfl_xor(v, 2);
            v += __shfl_xor(v, 4);
            v += __shfl_xor(v, 8);
            lr[r] = __builtin_amdgcn_rcpf(v);
        }
#pragma unroll
        for (int nt = 0; nt < 4; ++nt) {
            int d = nt * 16 + l16;
#pragma unroll
            for (int r = 0; r < 4; ++r) {
                int s = q0 + qs * 16 + quad * 4 + r;
                float v = o[qs][nt][r] * lr[r];
                Ou[(size_t)(b * SS + s) * DD + h * HDD + d] = f2bf(v);
            }
        }
    }
}

// ---------------------------------------------------------------------------
// Buffer plan.  TSZ = B*S*D bf16 = 16 MiB; WSZ = D*D bf16 = 2 MiB.
//   d_out (32 MiB fp32): [0,TSZ) = xb, [TSZ,2*TSZ) = Vt — both dead before
//     gemm_out overwrites d_out (it reads only Ob, wb3).
//   ws: Qb | Kb | Ob | wb0..3 = 56 MiB.  wb0..2 contiguous => W3 for QKV.
// ---------------------------------------------------------------------------
extern "C" void kernel_launch(void* const* d_in, const int* in_sizes, int n_in,
                              void* d_out, int out_size, void* d_ws,
                              size_t ws_size, hipStream_t stream)
{
    const float* x    = (const float*)d_in[0];
    const float* fcos = (const float*)d_in[1];
    const float* fsin = (const float*)d_in[2];
    const float* wq   = (const float*)d_in[3];
    const float* wk   = (const float*)d_in[4];
    const float* wv   = (const float*)d_in[5];
    const float* wo   = (const float*)d_in[6];

    char* ws = (char*)d_ws;
    const size_t TSZ = (size_t)BB * SS * DD * sizeof(bf16_t);  // 16 MiB
    const size_t WSZ = (size_t)DD * DD * sizeof(bf16_t);       // 2 MiB
    bf16_t* Qb  = (bf16_t*)(ws);
    bf16_t* Kb  = (bf16_t*)(ws + TSZ);
    bf16_t* Ob  = (bf16_t*)(ws + 2 * TSZ);
    bf16_t* wb0 = (bf16_t*)(ws + 3 * TSZ);
    bf16_t* wb1 = (bf16_t*)(ws + 3 * TSZ + WSZ);
    bf16_t* wb2 = (bf16_t*)(ws + 3 * TSZ + 2 * WSZ);
    bf16_t* wb3 = (bf16_t*)(ws + 3 * TSZ + 3 * WSZ);
    bf16_t* xb  = (bf16_t*)d_out;
    bf16_t* Vt  = (bf16_t*)((char*)d_out + TSZ);

    dim3 bb(256);
    cvt1<<<dim3(4096), bb, 0, stream>>>(x, xb);
    cvt4<<<dim3(512, 4), bb, 0, stream>>>(wq, wk, wv, wo, wb0, wb1, wb2, wb3);

    gemm_qkv<<<dim3(24, 64), bb, 0, stream>>>(xb, wb0, Qb, Kb, Vt, fcos, fsin);
    attn<<<dim3(2048), dim3(128), 0, stream>>>(Qb, Kb, Vt, Ob);
    gemm_out<<<dim3(8, 64), bb, 0, stream>>>(Ob, wb3, (float*)d_out);
}